// Round 1
// baseline (2271.305 us; speedup 1.0000x reference)
//
#include <hip/hip_runtime.h>

#define NN 50000
#define NE 800000
#define E2 (NE + NN)   // edges + self loops
#define IN_DIM 128

// ---------------- fill ----------------
__global__ __launch_bounds__(256) void fill_f32(float* __restrict__ p, float v, int n) {
    int i = blockIdx.x * 256 + threadIdx.x;
    if (i < n) p[i] = v;
}

// ---------------- GEMM: C[M,N] = A[M,K] @ W[K,N], f32 ----------------
#define BM 64
#define BN 64
#define BK 16
__global__ __launch_bounds__(256) void gemm_f32(const float* __restrict__ A,
                                                const float* __restrict__ W,
                                                float* __restrict__ C,
                                                int M, int K, int N) {
    __shared__ __align__(16) float As[BK][BM + 4];  // +4 pad keeps float4 alignment, kills conflicts
    __shared__ __align__(16) float Ws[BK][BN];
    int tid = threadIdx.x;
    int row0 = blockIdx.x * BM, col0 = blockIdx.y * BN;
    int tn = (tid & 15) * 4;
    int tm = (tid >> 4) * 4;
    int ar = tid >> 2;        // 0..63
    int ak = (tid & 3) * 4;   // 0,4,8,12
    int wk = tid >> 4;        // 0..15
    int wn = (tid & 15) * 4;
    float acc[4][4] = {};
    int arow = row0 + ar;
    for (int k0 = 0; k0 < K; k0 += BK) {
        float4 av = make_float4(0.f, 0.f, 0.f, 0.f);
        if (arow < M) av = *reinterpret_cast<const float4*>(A + (size_t)arow * K + k0 + ak);
        float4 wv = *reinterpret_cast<const float4*>(W + (size_t)(k0 + wk) * N + col0 + wn);
        __syncthreads();
        As[ak + 0][ar] = av.x; As[ak + 1][ar] = av.y;
        As[ak + 2][ar] = av.z; As[ak + 3][ar] = av.w;
        *reinterpret_cast<float4*>(&Ws[wk][wn]) = wv;
        __syncthreads();
#pragma unroll
        for (int kk = 0; kk < BK; ++kk) {
            float4 a = *reinterpret_cast<const float4*>(&As[kk][tm]);
            float4 w = *reinterpret_cast<const float4*>(&Ws[kk][tn]);
            acc[0][0] += a.x * w.x; acc[0][1] += a.x * w.y; acc[0][2] += a.x * w.z; acc[0][3] += a.x * w.w;
            acc[1][0] += a.y * w.x; acc[1][1] += a.y * w.y; acc[1][2] += a.y * w.z; acc[1][3] += a.y * w.w;
            acc[2][0] += a.z * w.x; acc[2][1] += a.z * w.y; acc[2][2] += a.z * w.z; acc[2][3] += a.z * w.w;
            acc[3][0] += a.w * w.x; acc[3][1] += a.w * w.y; acc[3][2] += a.w * w.z; acc[3][3] += a.w * w.w;
        }
    }
#pragma unroll
    for (int i = 0; i < 4; ++i) {
        int r = row0 + tm + i;
        if (r < M) {
            float4 o = make_float4(acc[i][0], acc[i][1], acc[i][2], acc[i][3]);
            *reinterpret_cast<float4*>(C + (size_t)r * N + col0 + tn) = o;
        }
    }
}

// ---------------- attention scores per node/head ----------------
// block = H*64 threads, one block per node; wave w handles head w
__global__ void escore(const float* __restrict__ h, const float* __restrict__ as,
                       const float* __restrict__ ad, float* __restrict__ es,
                       float* __restrict__ ed, int H) {
    int n = blockIdx.x;
    int t = threadIdx.x;
    int D = blockDim.x;
    float hv = h[(size_t)n * D + t];
    float vs = hv * as[t];
    float vd = hv * ad[t];
#pragma unroll
    for (int off = 32; off; off >>= 1) {
        vs += __shfl_down(vs, off);
        vd += __shfl_down(vd, off);
    }
    if ((t & 63) == 0) {
        int head = t >> 6;
        es[n * H + head] = vs;
        ed[n * H + head] = vd;
    }
}

// ---------------- atomic max on float ----------------
__device__ inline void atomicMaxF(float* addr, float val) {
    if (val >= 0.f) atomicMax((int*)addr, __float_as_int(val));
    else            atomicMin((unsigned int*)addr, __float_as_uint(val));
}

// ---------------- edge pass 1: leaky-relu score + segment max ----------------
__global__ __launch_bounds__(256) void edge_max(const int* __restrict__ ei,
                                                const float* __restrict__ es,
                                                const float* __restrict__ ed,
                                                float* __restrict__ ev,
                                                float* __restrict__ m,
                                                int H, int logH) {
    int idx = blockIdx.x * 256 + threadIdx.x;
    if (idx >= E2 * H) return;
    int e = idx >> logH;
    int hh = idx & (H - 1);
    int s, d;
    if (e < NE) { s = ei[e]; d = ei[NE + e]; } else { s = d = e - NE; }
    float v = es[s * H + hh] + ed[d * H + hh];
    v = v > 0.f ? v : 0.2f * v;
    ev[idx] = v;
    atomicMaxF(&m[d * H + hh], v);
}

// ---------------- edge pass 2: exp + segment sum ----------------
__global__ __launch_bounds__(256) void edge_sum(const int* __restrict__ ei,
                                                float* __restrict__ ev,
                                                const float* __restrict__ m,
                                                float* __restrict__ s_,
                                                int H, int logH) {
    int idx = blockIdx.x * 256 + threadIdx.x;
    if (idx >= E2 * H) return;
    int e = idx >> logH;
    int hh = idx & (H - 1);
    int d = (e < NE) ? ei[NE + e] : e - NE;
    float p = expf(ev[idx] - m[d * H + hh]);
    ev[idx] = p;
    atomicAdd(&s_[d * H + hh], p);
}

// ---------------- edge pass 3: weighted gather-scatter ----------------
__global__ __launch_bounds__(256) void edge_aggregate(const int* __restrict__ ei,
                                                      const float* __restrict__ ev,
                                                      const float* __restrict__ h,
                                                      float* __restrict__ agg,
                                                      int H, int D, int logD) {
    size_t idx = (size_t)blockIdx.x * 256 + threadIdx.x;
    if (idx >= (size_t)E2 * D) return;
    int e = (int)(idx >> logD);
    int f = (int)(idx & (D - 1));
    int s, d;
    if (e < NE) { s = ei[e]; d = ei[NE + e]; } else { s = d = e - NE; }
    float p = ev[e * H + (f >> 6)];
    atomicAdd(&agg[(size_t)d * D + f], p * h[(size_t)s * D + f]);
}

// ---------------- normalize + bias + relu ----------------
__global__ __launch_bounds__(256) void norm_bias_relu(float* __restrict__ agg,
                                                      const float* __restrict__ s,
                                                      const float* __restrict__ b,
                                                      int H, int D, int logD) {
    size_t idx = (size_t)blockIdx.x * 256 + threadIdx.x;
    if (idx >= (size_t)NN * D) return;
    int n = (int)(idx >> logD);
    int f = (int)(idx & (D - 1));
    float v = agg[idx] / (s[n * H + (f >> 6)] + 1e-16f) + b[f];
    agg[idx] = v > 0.f ? v : 0.f;
}

// ---------------- final FC: out = h @ fc_W + fc_b ----------------
__global__ __launch_bounds__(256) void fc_kernel(const float* __restrict__ h,
                                                 const float* __restrict__ W,
                                                 const float* __restrict__ b,
                                                 float* __restrict__ out) {
    int idx = blockIdx.x * 256 + threadIdx.x;
    if (idx >= NN * 10) return;
    int n = idx / 10, j = idx - n * 10;
    float acc = b[j];
#pragma unroll
    for (int c = 0; c < 64; ++c) acc += h[n * 64 + c] * W[c * 10 + j];
    out[idx] = acc;
}

extern "C" void kernel_launch(void* const* d_in, const int* in_sizes, int n_in,
                              void* d_out, int out_size, void* d_ws, size_t ws_size,
                              hipStream_t stream) {
    const float* x   = (const float*)d_in[0];
    const int*   ei  = (const int*)d_in[1];
    const float* W1  = (const float*)d_in[2];
    const float* a1s = (const float*)d_in[3];
    const float* a1d = (const float*)d_in[4];
    const float* b1  = (const float*)d_in[5];
    const float* W2  = (const float*)d_in[6];
    const float* a2s = (const float*)d_in[7];
    const float* a2d = (const float*)d_in[8];
    const float* b2  = (const float*)d_in[9];
    const float* W3  = (const float*)d_in[10];
    const float* a3s = (const float*)d_in[11];
    const float* a3d = (const float*)d_in[12];
    const float* b3  = (const float*)d_in[13];
    const float* fcW = (const float*)d_in[14];
    const float* fcb = (const float*)d_in[15];
    float* out = (float*)d_out;

    // workspace layout (floats): A(h) | B(act) | EV | ES | ED | M | S  -> ~119 MB
    float* A  = (float*)d_ws;
    float* B  = A  + (size_t)NN * 256;
    float* EV = B  + (size_t)NN * 256;
    float* ES = EV + (size_t)E2 * 4;
    float* ED = ES + (size_t)NN * 4;
    float* M_ = ED + (size_t)NN * 4;
    float* S_ = M_ + (size_t)NN * 4;

    auto run_layer = [&](const float* in, int K, int H, int logH,
                         const float* Wl, const float* as, const float* ad,
                         const float* bb, float* hbuf, float* obuf) {
        int D = H * 64;
        int logD = (D == 256) ? 8 : 6;
        dim3 g((NN + BM - 1) / BM, D / BN);
        gemm_f32<<<g, 256, 0, stream>>>(in, Wl, hbuf, NN, K, D);
        escore<<<NN, D, 0, stream>>>(hbuf, as, ad, ES, ED, H);
        int nh = NN * H;
        fill_f32<<<(nh + 255) / 256, 256, 0, stream>>>(M_, -1e30f, nh);
        fill_f32<<<(nh + 255) / 256, 256, 0, stream>>>(S_, 0.f, nh);
        int nd = NN * D;
        fill_f32<<<(nd + 255) / 256, 256, 0, stream>>>(obuf, 0.f, nd);
        int eh = E2 * H;
        edge_max<<<(eh + 255) / 256, 256, 0, stream>>>(ei, ES, ED, EV, M_, H, logH);
        edge_sum<<<(eh + 255) / 256, 256, 0, stream>>>(ei, EV, M_, S_, H, logH);
        size_t et = (size_t)E2 * D;
        edge_aggregate<<<(unsigned)((et + 255) / 256), 256, 0, stream>>>(ei, EV, hbuf, obuf, H, D, logD);
        norm_bias_relu<<<(nd + 255) / 256, 256, 0, stream>>>(obuf, S_, bb, H, D, logD);
    };

    run_layer(x, IN_DIM, 4, 2, W1, a1s, a1d, b1, A, B);
    run_layer(B, 256,    4, 2, W2, a2s, a2d, b2, A, B);
    run_layer(B, 256,    1, 0, W3, a3s, a3d, b3, A, B);
    fc_kernel<<<(NN * 10 + 255) / 256, 256, 0, stream>>>(B, fcW, fcb, out);
}

// Round 2
// 981.761 us; speedup vs baseline: 2.3135x; 2.3135x over previous
//
#include <hip/hip_runtime.h>

#define NN 50000
#define NE 800000
#define E2 (NE + NN)   // edges + self loops
#define IN_DIM 128

// ---------------- fills ----------------
__global__ __launch_bounds__(256) void fill_i32(int* __restrict__ p, int v, int n) {
    int i = blockIdx.x * 256 + threadIdx.x;
    if (i < n) p[i] = v;
}

// ---------------- CSR build ----------------
__global__ __launch_bounds__(256) void hist_dst(const int* __restrict__ ei, int* __restrict__ deg) {
    int e = blockIdx.x * 256 + threadIdx.x;
    if (e < NE) atomicAdd(&deg[ei[NE + e]], 1);
}

// single-block exclusive scan of deg[0..NN) -> rowptr, cursor
__global__ __launch_bounds__(1024) void scan50k(const int* __restrict__ deg,
                                                int* __restrict__ rowptr,
                                                int* __restrict__ cursor) {
    __shared__ int part[1024];
    const int C = (NN + 1023) / 1024;
    int t = threadIdx.x;
    int base = t * C;
    int sum = 0;
    for (int k = 0; k < C; ++k) { int idx = base + k; if (idx < NN) sum += deg[idx]; }
    part[t] = sum;
    __syncthreads();
    for (int off = 1; off < 1024; off <<= 1) {
        int v = (t >= off) ? part[t - off] : 0;
        __syncthreads();
        part[t] += v;
        __syncthreads();
    }
    int excl = (t == 0) ? 0 : part[t - 1];
    for (int k = 0; k < C; ++k) {
        int idx = base + k;
        if (idx < NN) { rowptr[idx] = excl; cursor[idx] = excl; excl += deg[idx]; }
    }
    if (t == 1023) rowptr[NN] = E2;
}

__global__ __launch_bounds__(256) void scatter_csr(const int* __restrict__ ei,
                                                   int* __restrict__ cursor,
                                                   int* __restrict__ csr_src) {
    int e = blockIdx.x * 256 + threadIdx.x;
    if (e >= E2) return;
    int s, d;
    if (e < NE) { s = ei[e]; d = ei[NE + e]; } else { s = d = e - NE; }
    int pos = atomicAdd(&cursor[d], 1);
    csr_src[pos] = s;
}

// ---------------- GEMM: C[M,N] = A[M,K] @ W[K,N], f32 ----------------
#define BM 64
#define BN 64
#define BK 16
__global__ __launch_bounds__(256) void gemm_f32(const float* __restrict__ A,
                                                const float* __restrict__ W,
                                                float* __restrict__ C,
                                                int M, int K, int N) {
    __shared__ __align__(16) float As[BK][BM + 4];
    __shared__ __align__(16) float Ws[BK][BN];
    int tid = threadIdx.x;
    int row0 = blockIdx.x * BM, col0 = blockIdx.y * BN;
    int tn = (tid & 15) * 4;
    int tm = (tid >> 4) * 4;
    int ar = tid >> 2;
    int ak = (tid & 3) * 4;
    int wk = tid >> 4;
    int wn = (tid & 15) * 4;
    float acc[4][4] = {};
    int arow = row0 + ar;
    for (int k0 = 0; k0 < K; k0 += BK) {
        float4 av = make_float4(0.f, 0.f, 0.f, 0.f);
        if (arow < M) av = *reinterpret_cast<const float4*>(A + (size_t)arow * K + k0 + ak);
        float4 wv = *reinterpret_cast<const float4*>(W + (size_t)(k0 + wk) * N + col0 + wn);
        __syncthreads();
        As[ak + 0][ar] = av.x; As[ak + 1][ar] = av.y;
        As[ak + 2][ar] = av.z; As[ak + 3][ar] = av.w;
        *reinterpret_cast<float4*>(&Ws[wk][wn]) = wv;
        __syncthreads();
#pragma unroll
        for (int kk = 0; kk < BK; ++kk) {
            float4 a = *reinterpret_cast<const float4*>(&As[kk][tm]);
            float4 w = *reinterpret_cast<const float4*>(&Ws[kk][tn]);
            acc[0][0] += a.x * w.x; acc[0][1] += a.x * w.y; acc[0][2] += a.x * w.z; acc[0][3] += a.x * w.w;
            acc[1][0] += a.y * w.x; acc[1][1] += a.y * w.y; acc[1][2] += a.y * w.z; acc[1][3] += a.y * w.w;
            acc[2][0] += a.z * w.x; acc[2][1] += a.z * w.y; acc[2][2] += a.z * w.z; acc[2][3] += a.z * w.w;
            acc[3][0] += a.w * w.x; acc[3][1] += a.w * w.y; acc[3][2] += a.w * w.z; acc[3][3] += a.w * w.w;
        }
    }
#pragma unroll
    for (int i = 0; i < 4; ++i) {
        int r = row0 + tm + i;
        if (r < M) {
            float4 o = make_float4(acc[i][0], acc[i][1], acc[i][2], acc[i][3]);
            *reinterpret_cast<float4*>(C + (size_t)r * N + col0 + tn) = o;
        }
    }
}

// ---------------- attention scores per node/head ----------------
__global__ void escore(const float* __restrict__ h, const float* __restrict__ as,
                       const float* __restrict__ ad, float* __restrict__ es,
                       float* __restrict__ ed, int H) {
    int n = blockIdx.x;
    int t = threadIdx.x;
    int D = blockDim.x;
    float hv = h[(size_t)n * D + t];
    float vs = hv * as[t];
    float vd = hv * ad[t];
#pragma unroll
    for (int off = 32; off; off >>= 1) {
        vs += __shfl_down(vs, off);
        vd += __shfl_down(vd, off);
    }
    if ((t & 63) == 0) {
        int head = t >> 6;
        es[n * H + head] = vs;
        ed[n * H + head] = vd;
    }
}

// ---------------- fused per-node softmax over incoming edges (CSR) ----------------
// one wave per node; within the wave, 64/H threads per head
__global__ __launch_bounds__(256) void attn_csr(const int* __restrict__ rowptr,
                                                const int* __restrict__ csr_src,
                                                const float* __restrict__ es,
                                                const float* __restrict__ ed,
                                                float* __restrict__ ev,
                                                float* __restrict__ s_,
                                                int H, int logH) {
    int wid = threadIdx.x >> 6;
    int lane = threadIdx.x & 63;
    int n = blockIdx.x * 4 + wid;
    if (n >= NN) return;
    int head = lane & (H - 1);
    int j = lane >> logH;
    int JP = 64 >> logH;
    int start = rowptr[n], end = rowptr[n + 1];
    float edv = ed[n * H + head];
    float m = -1e30f;
    for (int i = start + j; i < end; i += JP) {
        int src = csr_src[i];
        float v = es[src * H + head] + edv;
        v = v > 0.f ? v : 0.2f * v;
        m = fmaxf(m, v);
    }
#pragma unroll
    for (int off = 1; off < 64; off <<= 1)
        if (off >= H) m = fmaxf(m, __shfl_xor(m, off));
    float sum = 0.f;
    for (int i = start + j; i < end; i += JP) {
        int src = csr_src[i];
        float v = es[src * H + head] + edv;
        v = v > 0.f ? v : 0.2f * v;
        float p = __expf(v - m);
        ev[i * H + head] = p;
        sum += p;
    }
#pragma unroll
    for (int off = 1; off < 64; off <<= 1)
        if (off >= H) sum += __shfl_xor(sum, off);
    if (lane < H) s_[n * H + lane] = sum;
}

// ---------------- CSR aggregate + normalize + bias + relu ----------------
// D=256: one block per node; D=64: 4 nodes per block (one wave each)
__global__ __launch_bounds__(256) void agg_csr(const int* __restrict__ rowptr,
                                               const int* __restrict__ csr_src,
                                               const float* __restrict__ ev,
                                               const float* __restrict__ h,
                                               const float* __restrict__ s_,
                                               const float* __restrict__ b,
                                               float* __restrict__ out,
                                               int H, int D, int logD) {
    int tid = threadIdx.x;
    int npb = 256 >> logD;
    int n = blockIdx.x * npb + (tid >> logD);
    if (n >= NN) return;
    int f = tid & (D - 1);
    int head = f >> 6;
    int start = rowptr[n], end = rowptr[n + 1];
    float acc = 0.f;
    int i = start;
    for (; i + 1 < end; i += 2) {
        int s0 = csr_src[i], s1 = csr_src[i + 1];
        float p0 = ev[i * H + head], p1 = ev[(i + 1) * H + head];
        float h0 = h[((size_t)s0 << logD) | f];
        float h1 = h[((size_t)s1 << logD) | f];
        acc += p0 * h0;
        acc += p1 * h1;
    }
    if (i < end) {
        int s0 = csr_src[i];
        acc += ev[i * H + head] * h[((size_t)s0 << logD) | f];
    }
    float v = acc / (s_[n * H + head] + 1e-16f) + b[f];
    out[((size_t)n << logD) | f] = v > 0.f ? v : 0.f;
}

// ---------------- final FC: out = h @ fc_W + fc_b ----------------
__global__ __launch_bounds__(256) void fc_kernel(const float* __restrict__ h,
                                                 const float* __restrict__ W,
                                                 const float* __restrict__ b,
                                                 float* __restrict__ out) {
    int idx = blockIdx.x * 256 + threadIdx.x;
    if (idx >= NN * 10) return;
    int n = idx / 10, j = idx - n * 10;
    float acc = b[j];
#pragma unroll
    for (int c = 0; c < 64; ++c) acc += h[n * 64 + c] * W[c * 10 + j];
    out[idx] = acc;
}

extern "C" void kernel_launch(void* const* d_in, const int* in_sizes, int n_in,
                              void* d_out, int out_size, void* d_ws, size_t ws_size,
                              hipStream_t stream) {
    const float* x   = (const float*)d_in[0];
    const int*   ei  = (const int*)d_in[1];
    const float* W1  = (const float*)d_in[2];
    const float* a1s = (const float*)d_in[3];
    const float* a1d = (const float*)d_in[4];
    const float* b1  = (const float*)d_in[5];
    const float* W2  = (const float*)d_in[6];
    const float* a2s = (const float*)d_in[7];
    const float* a2d = (const float*)d_in[8];
    const float* b2  = (const float*)d_in[9];
    const float* W3  = (const float*)d_in[10];
    const float* a3s = (const float*)d_in[11];
    const float* a3d = (const float*)d_in[12];
    const float* b3  = (const float*)d_in[13];
    const float* fcW = (const float*)d_in[14];
    const float* fcb = (const float*)d_in[15];
    float* out = (float*)d_out;

    // workspace layout (floats/ints)
    float* A      = (float*)d_ws;                    // h buffer      [NN*256]
    float* B      = A + (size_t)NN * 256;            // activations   [NN*256]
    float* EV     = B + (size_t)NN * 256;            // p, CSR order  [E2*4]
    float* ES     = EV + (size_t)E2 * 4;             // [NN*4]
    float* ED     = ES + (size_t)NN * 4;             // [NN*4]
    float* S_     = ED + (size_t)NN * 4;             // [NN*4]
    int*   rowptr = (int*)(S_ + (size_t)NN * 4);     // [NN+1]
    int*   csrsrc = rowptr + (NN + 1);               // [E2]
    int*   deg    = csrsrc + E2;                     // [NN]
    int*   cursor = (int*)ES;                        // alias (used only before layers)

    // ---- build CSR (same for all layers) ----
    fill_i32<<<(NN + 255) / 256, 256, 0, stream>>>(deg, 1, NN);  // self-loops
    hist_dst<<<(NE + 255) / 256, 256, 0, stream>>>(ei, deg);
    scan50k<<<1, 1024, 0, stream>>>(deg, rowptr, cursor);
    scatter_csr<<<(E2 + 255) / 256, 256, 0, stream>>>(ei, cursor, csrsrc);

    auto run_layer = [&](const float* in, int K, int H, int logH,
                         const float* Wl, const float* as, const float* ad,
                         const float* bb, float* hbuf, float* obuf) {
        int D = H * 64;
        int logD = (D == 256) ? 8 : 6;
        dim3 g((NN + BM - 1) / BM, D / BN);
        gemm_f32<<<g, 256, 0, stream>>>(in, Wl, hbuf, NN, K, D);
        escore<<<NN, D, 0, stream>>>(hbuf, as, ad, ES, ED, H);
        attn_csr<<<(NN + 3) / 4, 256, 0, stream>>>(rowptr, csrsrc, ES, ED, EV, S_, H, logH);
        int npb = 256 >> logD;
        agg_csr<<<(NN + npb - 1) / npb, 256, 0, stream>>>(rowptr, csrsrc, EV, hbuf, S_, bb, obuf, H, D, logD);
    };

    run_layer(x, IN_DIM, 4, 2, W1, a1s, a1d, b1, A, B);
    run_layer(B, 256,    4, 2, W2, a2s, a2d, b2, A, B);
    run_layer(B, 256,    1, 0, W3, a3s, a3d, b3, A, B);
    fc_kernel<<<(NN * 10 + 255) / 256, 256, 0, stream>>>(B, fcW, fcb, out);
}

// Round 3
// 847.327 us; speedup vs baseline: 2.6806x; 1.1587x over previous
//
#include <hip/hip_runtime.h>

#define NN 50000
#define NE 800000
#define E2 (NE + NN)   // edges + self loops
#define IN_DIM 128

// ---------------- fills ----------------
__global__ __launch_bounds__(256) void fill_i32(int* __restrict__ p, int v, int n) {
    int i = blockIdx.x * 256 + threadIdx.x;
    if (i < n) p[i] = v;
}

// ---------------- CSR build ----------------
__global__ __launch_bounds__(256) void hist_dst(const int* __restrict__ ei, int* __restrict__ deg) {
    int e = blockIdx.x * 256 + threadIdx.x;
    if (e < NE) atomicAdd(&deg[ei[NE + e]], 1);
}

__global__ __launch_bounds__(1024) void scan50k(const int* __restrict__ deg,
                                                int* __restrict__ rowptr,
                                                int* __restrict__ cursor) {
    __shared__ int part[1024];
    const int C = (NN + 1023) / 1024;
    int t = threadIdx.x;
    int base = t * C;
    int sum = 0;
    for (int k = 0; k < C; ++k) { int idx = base + k; if (idx < NN) sum += deg[idx]; }
    part[t] = sum;
    __syncthreads();
    for (int off = 1; off < 1024; off <<= 1) {
        int v = (t >= off) ? part[t - off] : 0;
        __syncthreads();
        part[t] += v;
        __syncthreads();
    }
    int excl = (t == 0) ? 0 : part[t - 1];
    for (int k = 0; k < C; ++k) {
        int idx = base + k;
        if (idx < NN) { rowptr[idx] = excl; cursor[idx] = excl; excl += deg[idx]; }
    }
    if (t == 1023) rowptr[NN] = E2;
}

__global__ __launch_bounds__(256) void scatter_csr(const int* __restrict__ ei,
                                                   int* __restrict__ cursor,
                                                   int* __restrict__ csr_src) {
    int e = blockIdx.x * 256 + threadIdx.x;
    if (e >= E2) return;
    int s, d;
    if (e < NE) { s = ei[e]; d = ei[NE + e]; } else { s = d = e - NE; }
    int pos = atomicAdd(&cursor[d], 1);
    csr_src[pos] = s;
}

// ---------------- GEMM 128x128 tile, 8x8 per thread ----------------
#define GBM 128
#define GBN 128
#define GBK 16
__global__ __launch_bounds__(256) void gemm128(const float* __restrict__ A,
                                               const float* __restrict__ W,
                                               float* __restrict__ C,
                                               int M, int K, int N) {
    __shared__ __align__(16) float As[GBK][GBM + 4];
    __shared__ __align__(16) float Ws[GBK][GBN];
    int tid = threadIdx.x;
    int row0 = blockIdx.x * GBM, col0 = blockIdx.y * GBN;
    int ar = tid >> 1, ak = (tid & 1) * 8;       // A staging: row, k-offset
    int wk = tid >> 4, wn = (tid & 15) * 8;      // W staging
    int tm = (tid >> 4) * 8, tn = (tid & 15) * 8; // compute tile
    float acc[8][8] = {};
    int arow = row0 + ar;
    const float* Abase = A + (size_t)arow * K + ak;
    for (int k0 = 0; k0 < K; k0 += GBK) {
        float4 a0 = make_float4(0.f, 0.f, 0.f, 0.f), a1 = a0;
        if (arow < M) {
            a0 = *reinterpret_cast<const float4*>(Abase + k0);
            a1 = *reinterpret_cast<const float4*>(Abase + k0 + 4);
        }
        const float* Wp = W + (size_t)(k0 + wk) * N + col0 + wn;
        float4 w0 = *reinterpret_cast<const float4*>(Wp);
        float4 w1 = *reinterpret_cast<const float4*>(Wp + 4);
        __syncthreads();
        As[ak + 0][ar] = a0.x; As[ak + 1][ar] = a0.y;
        As[ak + 2][ar] = a0.z; As[ak + 3][ar] = a0.w;
        As[ak + 4][ar] = a1.x; As[ak + 5][ar] = a1.y;
        As[ak + 6][ar] = a1.z; As[ak + 7][ar] = a1.w;
        *reinterpret_cast<float4*>(&Ws[wk][wn]) = w0;
        *reinterpret_cast<float4*>(&Ws[wk][wn + 4]) = w1;
        __syncthreads();
#pragma unroll
        for (int kk = 0; kk < GBK; ++kk) {
            float4 x0 = *reinterpret_cast<const float4*>(&As[kk][tm]);
            float4 x1 = *reinterpret_cast<const float4*>(&As[kk][tm + 4]);
            float4 y0 = *reinterpret_cast<const float4*>(&Ws[kk][tn]);
            float4 y1 = *reinterpret_cast<const float4*>(&Ws[kk][tn + 4]);
            float xa[8] = {x0.x, x0.y, x0.z, x0.w, x1.x, x1.y, x1.z, x1.w};
            float yb[8] = {y0.x, y0.y, y0.z, y0.w, y1.x, y1.y, y1.z, y1.w};
#pragma unroll
            for (int i = 0; i < 8; ++i)
#pragma unroll
                for (int j = 0; j < 8; ++j)
                    acc[i][j] += xa[i] * yb[j];
        }
    }
#pragma unroll
    for (int i = 0; i < 8; ++i) {
        int r = row0 + tm + i;
        if (r < M) {
            float4 o0 = make_float4(acc[i][0], acc[i][1], acc[i][2], acc[i][3]);
            float4 o1 = make_float4(acc[i][4], acc[i][5], acc[i][6], acc[i][7]);
            *reinterpret_cast<float4*>(C + (size_t)r * N + col0 + tn) = o0;
            *reinterpret_cast<float4*>(C + (size_t)r * N + col0 + tn + 4) = o1;
        }
    }
}

// ---------------- GEMM 64x64 (for N=64 layer) ----------------
#define BM 64
#define BN 64
#define BK 16
__global__ __launch_bounds__(256) void gemm_f32(const float* __restrict__ A,
                                                const float* __restrict__ W,
                                                float* __restrict__ C,
                                                int M, int K, int N) {
    __shared__ __align__(16) float As[BK][BM + 4];
    __shared__ __align__(16) float Ws[BK][BN];
    int tid = threadIdx.x;
    int row0 = blockIdx.x * BM, col0 = blockIdx.y * BN;
    int tn = (tid & 15) * 4;
    int tm = (tid >> 4) * 4;
    int ar = tid >> 2;
    int ak = (tid & 3) * 4;
    int wk = tid >> 4;
    int wn = (tid & 15) * 4;
    float acc[4][4] = {};
    int arow = row0 + ar;
    for (int k0 = 0; k0 < K; k0 += BK) {
        float4 av = make_float4(0.f, 0.f, 0.f, 0.f);
        if (arow < M) av = *reinterpret_cast<const float4*>(A + (size_t)arow * K + k0 + ak);
        float4 wv = *reinterpret_cast<const float4*>(W + (size_t)(k0 + wk) * N + col0 + wn);
        __syncthreads();
        As[ak + 0][ar] = av.x; As[ak + 1][ar] = av.y;
        As[ak + 2][ar] = av.z; As[ak + 3][ar] = av.w;
        *reinterpret_cast<float4*>(&Ws[wk][wn]) = wv;
        __syncthreads();
#pragma unroll
        for (int kk = 0; kk < BK; ++kk) {
            float4 a = *reinterpret_cast<const float4*>(&As[kk][tm]);
            float4 w = *reinterpret_cast<const float4*>(&Ws[kk][tn]);
            acc[0][0] += a.x * w.x; acc[0][1] += a.x * w.y; acc[0][2] += a.x * w.z; acc[0][3] += a.x * w.w;
            acc[1][0] += a.y * w.x; acc[1][1] += a.y * w.y; acc[1][2] += a.y * w.z; acc[1][3] += a.y * w.w;
            acc[2][0] += a.z * w.x; acc[2][1] += a.z * w.y; acc[2][2] += a.z * w.z; acc[2][3] += a.z * w.w;
            acc[3][0] += a.w * w.x; acc[3][1] += a.w * w.y; acc[3][2] += a.w * w.z; acc[3][3] += a.w * w.w;
        }
    }
#pragma unroll
    for (int i = 0; i < 4; ++i) {
        int r = row0 + tm + i;
        if (r < M) {
            float4 o = make_float4(acc[i][0], acc[i][1], acc[i][2], acc[i][3]);
            *reinterpret_cast<float4*>(C + (size_t)r * N + col0 + tn) = o;
        }
    }
}

// ---------------- attention scores per node/head ----------------
__global__ void escore(const float* __restrict__ h, const float* __restrict__ as,
                       const float* __restrict__ ad, float* __restrict__ es,
                       float* __restrict__ ed, int H) {
    int n = blockIdx.x;
    int t = threadIdx.x;
    int D = blockDim.x;
    float hv = h[(size_t)n * D + t];
    float vs = hv * as[t];
    float vd = hv * ad[t];
#pragma unroll
    for (int off = 32; off; off >>= 1) {
        vs += __shfl_down(vs, off);
        vd += __shfl_down(vd, off);
    }
    if ((t & 63) == 0) {
        int head = t >> 6;
        es[n * H + head] = vs;
        ed[n * H + head] = vd;
    }
}

// ---------------- fused per-node softmax over incoming edges (CSR) ----------------
__global__ __launch_bounds__(256) void attn_csr(const int* __restrict__ rowptr,
                                                const int* __restrict__ csr_src,
                                                const float* __restrict__ es,
                                                const float* __restrict__ ed,
                                                float* __restrict__ ev,
                                                float* __restrict__ s_,
                                                int H, int logH) {
    int wid = threadIdx.x >> 6;
    int lane = threadIdx.x & 63;
    int n = blockIdx.x * 4 + wid;
    if (n >= NN) return;
    int head = lane & (H - 1);
    int j = lane >> logH;
    int JP = 64 >> logH;
    int start = rowptr[n], end = rowptr[n + 1];
    float edv = ed[n * H + head];
    float m = -1e30f;
    for (int i = start + j; i < end; i += JP) {
        int src = csr_src[i];
        float v = es[src * H + head] + edv;
        v = v > 0.f ? v : 0.2f * v;
        m = fmaxf(m, v);
    }
#pragma unroll
    for (int off = 1; off < 64; off <<= 1)
        if (off >= H) m = fmaxf(m, __shfl_xor(m, off));
    float sum = 0.f;
    for (int i = start + j; i < end; i += JP) {
        int src = csr_src[i];
        float v = es[src * H + head] + edv;
        v = v > 0.f ? v : 0.2f * v;
        float p = __expf(v - m);
        ev[i * H + head] = p;
        sum += p;
    }
#pragma unroll
    for (int off = 1; off < 64; off <<= 1)
        if (off >= H) sum += __shfl_xor(sum, off);
    if (lane < H) s_[n * H + lane] = sum;
}

// ---------------- CSR aggregate (float4/thread) + normalize + bias + relu ----------------
template<int D, int H>
__global__ __launch_bounds__(256) void agg_csr4(const int* __restrict__ rowptr,
                                                const int* __restrict__ csr_src,
                                                const float* __restrict__ ev,
                                                const float* __restrict__ h,
                                                const float* __restrict__ s_,
                                                const float* __restrict__ b,
                                                float* __restrict__ out) {
    const int TPN = D / 4;       // threads per node
    const int NPB = 256 / TPN;   // nodes per block
    int tid = threadIdx.x;
    int n = blockIdx.x * NPB + tid / TPN;
    if (n >= NN) return;
    int f0 = (tid % TPN) * 4;
    int head = f0 >> 6;
    int start = rowptr[n], end = rowptr[n + 1];
    float4 acc = make_float4(0.f, 0.f, 0.f, 0.f);
    int i = start;
    for (; i + 3 < end; i += 4) {
        int s0 = csr_src[i], s1 = csr_src[i + 1], s2 = csr_src[i + 2], s3 = csr_src[i + 3];
        float p0 = ev[i * H + head];
        float p1 = ev[(i + 1) * H + head];
        float p2 = ev[(i + 2) * H + head];
        float p3 = ev[(i + 3) * H + head];
        float4 h0 = *reinterpret_cast<const float4*>(h + (size_t)s0 * D + f0);
        float4 h1 = *reinterpret_cast<const float4*>(h + (size_t)s1 * D + f0);
        float4 h2 = *reinterpret_cast<const float4*>(h + (size_t)s2 * D + f0);
        float4 h3 = *reinterpret_cast<const float4*>(h + (size_t)s3 * D + f0);
        acc.x += p0 * h0.x + p1 * h1.x + p2 * h2.x + p3 * h3.x;
        acc.y += p0 * h0.y + p1 * h1.y + p2 * h2.y + p3 * h3.y;
        acc.z += p0 * h0.z + p1 * h1.z + p2 * h2.z + p3 * h3.z;
        acc.w += p0 * h0.w + p1 * h1.w + p2 * h2.w + p3 * h3.w;
    }
    for (; i < end; ++i) {
        int s0 = csr_src[i];
        float p0 = ev[i * H + head];
        float4 h0 = *reinterpret_cast<const float4*>(h + (size_t)s0 * D + f0);
        acc.x += p0 * h0.x; acc.y += p0 * h0.y; acc.z += p0 * h0.z; acc.w += p0 * h0.w;
    }
    float inv = 1.f / (s_[n * H + head] + 1e-16f);
    float4 bb = *reinterpret_cast<const float4*>(b + f0);
    float4 o;
    o.x = acc.x * inv + bb.x; o.y = acc.y * inv + bb.y;
    o.z = acc.z * inv + bb.z; o.w = acc.w * inv + bb.w;
    o.x = o.x > 0.f ? o.x : 0.f; o.y = o.y > 0.f ? o.y : 0.f;
    o.z = o.z > 0.f ? o.z : 0.f; o.w = o.w > 0.f ? o.w : 0.f;
    *reinterpret_cast<float4*>(out + (size_t)n * D + f0) = o;
}

// ---------------- final FC: out = h @ fc_W + fc_b ----------------
__global__ __launch_bounds__(256) void fc_kernel(const float* __restrict__ h,
                                                 const float* __restrict__ W,
                                                 const float* __restrict__ b,
                                                 float* __restrict__ out) {
    int idx = blockIdx.x * 256 + threadIdx.x;
    if (idx >= NN * 10) return;
    int n = idx / 10, j = idx - n * 10;
    float acc = b[j];
#pragma unroll
    for (int c = 0; c < 64; ++c) acc += h[n * 64 + c] * W[c * 10 + j];
    out[idx] = acc;
}

extern "C" void kernel_launch(void* const* d_in, const int* in_sizes, int n_in,
                              void* d_out, int out_size, void* d_ws, size_t ws_size,
                              hipStream_t stream) {
    const float* x   = (const float*)d_in[0];
    const int*   ei  = (const int*)d_in[1];
    const float* W1  = (const float*)d_in[2];
    const float* a1s = (const float*)d_in[3];
    const float* a1d = (const float*)d_in[4];
    const float* b1  = (const float*)d_in[5];
    const float* W2  = (const float*)d_in[6];
    const float* a2s = (const float*)d_in[7];
    const float* a2d = (const float*)d_in[8];
    const float* b2  = (const float*)d_in[9];
    const float* W3  = (const float*)d_in[10];
    const float* a3s = (const float*)d_in[11];
    const float* a3d = (const float*)d_in[12];
    const float* b3  = (const float*)d_in[13];
    const float* fcW = (const float*)d_in[14];
    const float* fcb = (const float*)d_in[15];
    float* out = (float*)d_out;

    float* A      = (float*)d_ws;                    // h buffer      [NN*256]
    float* B      = A + (size_t)NN * 256;            // activations   [NN*256]
    float* EV     = B + (size_t)NN * 256;            // p, CSR order  [E2*4]
    float* ES     = EV + (size_t)E2 * 4;             // [NN*4]
    float* ED     = ES + (size_t)NN * 4;             // [NN*4]
    float* S_     = ED + (size_t)NN * 4;             // [NN*4]
    int*   rowptr = (int*)(S_ + (size_t)NN * 4);     // [NN+1]
    int*   csrsrc = rowptr + (NN + 1);               // [E2]
    int*   deg    = csrsrc + E2;                     // [NN]
    int*   cursor = (int*)ES;                        // alias (pre-layer only)

    // ---- build CSR ----
    fill_i32<<<(NN + 255) / 256, 256, 0, stream>>>(deg, 1, NN);
    hist_dst<<<(NE + 255) / 256, 256, 0, stream>>>(ei, deg);
    scan50k<<<1, 1024, 0, stream>>>(deg, rowptr, cursor);
    scatter_csr<<<(E2 + 255) / 256, 256, 0, stream>>>(ei, cursor, csrsrc);

    auto run_layer = [&](const float* in, int K, int H, int logH,
                         const float* Wl, const float* as, const float* ad,
                         const float* bb, float* hbuf, float* obuf) {
        int D = H * 64;
        if (D == 256) {
            dim3 g((NN + GBM - 1) / GBM, D / GBN);
            gemm128<<<g, 256, 0, stream>>>(in, Wl, hbuf, NN, K, D);
        } else {
            dim3 g((NN + BM - 1) / BM, D / BN);
            gemm_f32<<<g, 256, 0, stream>>>(in, Wl, hbuf, NN, K, D);
        }
        escore<<<NN, D, 0, stream>>>(hbuf, as, ad, ES, ED, H);
        attn_csr<<<(NN + 3) / 4, 256, 0, stream>>>(rowptr, csrsrc, ES, ED, EV, S_, H, logH);
        if (D == 256) {
            agg_csr4<256, 4><<<(NN + 3) / 4, 256, 0, stream>>>(rowptr, csrsrc, EV, hbuf, S_, bb, obuf);
        } else {
            agg_csr4<64, 1><<<(NN + 15) / 16, 256, 0, stream>>>(rowptr, csrsrc, EV, hbuf, S_, bb, obuf);
        }
    };

    run_layer(x, IN_DIM, 4, 2, W1, a1s, a1d, b1, A, B);
    run_layer(B, 256,    4, 2, W2, a2s, a2d, b2, A, B);
    run_layer(B, 256,    1, 0, W3, a3s, a3d, b3, A, B);
    fc_kernel<<<(NN * 10 + 255) / 256, 256, 0, stream>>>(B, fcW, fcb, out);
}

// Round 4
// 726.830 us; speedup vs baseline: 3.1249x; 1.1658x over previous
//
#include <hip/hip_runtime.h>

#define NN 50000
#define NE 800000
#define E2 (NE + NN)   // edges + self loops
#define IN_DIM 128
#define SCAN_B 196     // ceil(NN/256)

// ---------------- fills ----------------
__global__ __launch_bounds__(256) void fill_i32(int* __restrict__ p, int v, int n) {
    int i = blockIdx.x * 256 + threadIdx.x;
    if (i < n) p[i] = v;
}

// ---------------- CSR build ----------------
__global__ __launch_bounds__(256) void hist_dst(const int* __restrict__ ei, int* __restrict__ deg) {
    int e = blockIdx.x * 256 + threadIdx.x;
    if (e < NE) atomicAdd(&deg[ei[NE + e]], 1);
}

// pass B: per-block (256-elem) sums of deg
__global__ __launch_bounds__(256) void block_sums(const int* __restrict__ deg, int* __restrict__ bsum) {
    int b = blockIdx.x;
    int i = b * 256 + threadIdx.x;
    int v = (i < NN) ? deg[i] : 0;
#pragma unroll
    for (int off = 32; off; off >>= 1) v += __shfl_down(v, off);
    __shared__ int ws[4];
    if ((threadIdx.x & 63) == 0) ws[threadIdx.x >> 6] = v;
    __syncthreads();
    if (threadIdx.x == 0) bsum[b] = ws[0] + ws[1] + ws[2] + ws[3];
}

// pass C: exclusive scan of the SCAN_B block sums (single block)
__global__ __launch_bounds__(256) void scan_bsums(const int* __restrict__ bsum, int* __restrict__ boff) {
    __shared__ int s[256];
    int t = threadIdx.x;
    int v = (t < SCAN_B) ? bsum[t] : 0;
    s[t] = v;
    __syncthreads();
    for (int off = 1; off < 256; off <<= 1) {
        int u = (t >= off) ? s[t - off] : 0;
        __syncthreads();
        s[t] += u;
        __syncthreads();
    }
    if (t < SCAN_B) boff[t] = s[t] - v;
}

// pass D: per-block exclusive scan + global offset -> rowptr, cursor
__global__ __launch_bounds__(256) void scan_final(const int* __restrict__ deg,
                                                  const int* __restrict__ boff,
                                                  int* __restrict__ rowptr,
                                                  int* __restrict__ cursor) {
    int b = blockIdx.x;
    int t = threadIdx.x;
    int i = b * 256 + t;
    int v = (i < NN) ? deg[i] : 0;
    __shared__ int s[256];
    s[t] = v;
    __syncthreads();
    for (int off = 1; off < 256; off <<= 1) {
        int u = (t >= off) ? s[t - off] : 0;
        __syncthreads();
        s[t] += u;
        __syncthreads();
    }
    int excl = s[t] - v + boff[b];
    if (i < NN) { rowptr[i] = excl; cursor[i] = excl; }
    if (i == NN - 1) rowptr[NN] = excl + v;
}

__global__ __launch_bounds__(256) void scatter_csr(const int* __restrict__ ei,
                                                   int* __restrict__ cursor,
                                                   int* __restrict__ csr_src) {
    int e = blockIdx.x * 256 + threadIdx.x;
    if (e >= E2) return;
    int s, d;
    if (e < NE) { s = ei[e]; d = ei[NE + e]; } else { s = d = e - NE; }
    int pos = atomicAdd(&cursor[d], 1);
    csr_src[pos] = s;
}

// ---------------- GEMM 128x128 tile, 8x8 per thread ----------------
#define GBM 128
#define GBN 128
#define GBK 16
__global__ __launch_bounds__(256) void gemm128(const float* __restrict__ A,
                                               const float* __restrict__ W,
                                               float* __restrict__ C,
                                               int M, int K, int N) {
    __shared__ __align__(16) float As[GBK][GBM + 4];
    __shared__ __align__(16) float Ws[GBK][GBN];
    int tid = threadIdx.x;
    int row0 = blockIdx.x * GBM, col0 = blockIdx.y * GBN;
    int ar = tid >> 1, ak = (tid & 1) * 8;
    int wk = tid >> 4, wn = (tid & 15) * 8;
    int tm = (tid >> 4) * 8, tn = (tid & 15) * 8;
    float acc[8][8] = {};
    int arow = row0 + ar;
    const float* Abase = A + (size_t)arow * K + ak;
    for (int k0 = 0; k0 < K; k0 += GBK) {
        float4 a0 = make_float4(0.f, 0.f, 0.f, 0.f), a1 = a0;
        if (arow < M) {
            a0 = *reinterpret_cast<const float4*>(Abase + k0);
            a1 = *reinterpret_cast<const float4*>(Abase + k0 + 4);
        }
        const float* Wp = W + (size_t)(k0 + wk) * N + col0 + wn;
        float4 w0 = *reinterpret_cast<const float4*>(Wp);
        float4 w1 = *reinterpret_cast<const float4*>(Wp + 4);
        __syncthreads();
        As[ak + 0][ar] = a0.x; As[ak + 1][ar] = a0.y;
        As[ak + 2][ar] = a0.z; As[ak + 3][ar] = a0.w;
        As[ak + 4][ar] = a1.x; As[ak + 5][ar] = a1.y;
        As[ak + 6][ar] = a1.z; As[ak + 7][ar] = a1.w;
        *reinterpret_cast<float4*>(&Ws[wk][wn]) = w0;
        *reinterpret_cast<float4*>(&Ws[wk][wn + 4]) = w1;
        __syncthreads();
#pragma unroll
        for (int kk = 0; kk < GBK; ++kk) {
            float4 x0 = *reinterpret_cast<const float4*>(&As[kk][tm]);
            float4 x1 = *reinterpret_cast<const float4*>(&As[kk][tm + 4]);
            float4 y0 = *reinterpret_cast<const float4*>(&Ws[kk][tn]);
            float4 y1 = *reinterpret_cast<const float4*>(&Ws[kk][tn + 4]);
            float xa[8] = {x0.x, x0.y, x0.z, x0.w, x1.x, x1.y, x1.z, x1.w};
            float yb[8] = {y0.x, y0.y, y0.z, y0.w, y1.x, y1.y, y1.z, y1.w};
#pragma unroll
            for (int i = 0; i < 8; ++i)
#pragma unroll
                for (int j = 0; j < 8; ++j)
                    acc[i][j] += xa[i] * yb[j];
        }
    }
#pragma unroll
    for (int i = 0; i < 8; ++i) {
        int r = row0 + tm + i;
        if (r < M) {
            float4 o0 = make_float4(acc[i][0], acc[i][1], acc[i][2], acc[i][3]);
            float4 o1 = make_float4(acc[i][4], acc[i][5], acc[i][6], acc[i][7]);
            *reinterpret_cast<float4*>(C + (size_t)r * N + col0 + tn) = o0;
            *reinterpret_cast<float4*>(C + (size_t)r * N + col0 + tn + 4) = o1;
        }
    }
}

// ---------------- GEMM 64x64 (for N=64 layer) ----------------
#define BM 64
#define BN 64
#define BK 16
__global__ __launch_bounds__(256) void gemm_f32(const float* __restrict__ A,
                                                const float* __restrict__ W,
                                                float* __restrict__ C,
                                                int M, int K, int N) {
    __shared__ __align__(16) float As[BK][BM + 4];
    __shared__ __align__(16) float Ws[BK][BN];
    int tid = threadIdx.x;
    int row0 = blockIdx.x * BM, col0 = blockIdx.y * BN;
    int tn = (tid & 15) * 4;
    int tm = (tid >> 4) * 4;
    int ar = tid >> 2;
    int ak = (tid & 3) * 4;
    int wk = tid >> 4;
    int wn = (tid & 15) * 4;
    float acc[4][4] = {};
    int arow = row0 + ar;
    for (int k0 = 0; k0 < K; k0 += BK) {
        float4 av = make_float4(0.f, 0.f, 0.f, 0.f);
        if (arow < M) av = *reinterpret_cast<const float4*>(A + (size_t)arow * K + k0 + ak);
        float4 wv = *reinterpret_cast<const float4*>(W + (size_t)(k0 + wk) * N + col0 + wn);
        __syncthreads();
        As[ak + 0][ar] = av.x; As[ak + 1][ar] = av.y;
        As[ak + 2][ar] = av.z; As[ak + 3][ar] = av.w;
        *reinterpret_cast<float4*>(&Ws[wk][wn]) = wv;
        __syncthreads();
#pragma unroll
        for (int kk = 0; kk < BK; ++kk) {
            float4 a = *reinterpret_cast<const float4*>(&As[kk][tm]);
            float4 w = *reinterpret_cast<const float4*>(&Ws[kk][tn]);
            acc[0][0] += a.x * w.x; acc[0][1] += a.x * w.y; acc[0][2] += a.x * w.z; acc[0][3] += a.x * w.w;
            acc[1][0] += a.y * w.x; acc[1][1] += a.y * w.y; acc[1][2] += a.y * w.z; acc[1][3] += a.y * w.w;
            acc[2][0] += a.z * w.x; acc[2][1] += a.z * w.y; acc[2][2] += a.z * w.z; acc[2][3] += a.z * w.w;
            acc[3][0] += a.w * w.x; acc[3][1] += a.w * w.y; acc[3][2] += a.w * w.z; acc[3][3] += a.w * w.w;
        }
    }
#pragma unroll
    for (int i = 0; i < 4; ++i) {
        int r = row0 + tm + i;
        if (r < M) {
            float4 o = make_float4(acc[i][0], acc[i][1], acc[i][2], acc[i][3]);
            *reinterpret_cast<float4*>(C + (size_t)r * N + col0 + tn) = o;
        }
    }
}

// ---------------- attention scores per node/head ----------------
__global__ void escore(const float* __restrict__ h, const float* __restrict__ as,
                       const float* __restrict__ ad, float* __restrict__ es,
                       float* __restrict__ ed, int H) {
    int n = blockIdx.x;
    int t = threadIdx.x;
    int D = blockDim.x;
    float hv = h[(size_t)n * D + t];
    float vs = hv * as[t];
    float vd = hv * ad[t];
#pragma unroll
    for (int off = 32; off; off >>= 1) {
        vs += __shfl_down(vs, off);
        vd += __shfl_down(vd, off);
    }
    if ((t & 63) == 0) {
        int head = t >> 6;
        es[n * H + head] = vs;
        ed[n * H + head] = vd;
    }
}

// ---------------- fused per-node softmax over incoming edges (CSR) ----------------
__global__ __launch_bounds__(256) void attn_csr(const int* __restrict__ rowptr,
                                                const int* __restrict__ csr_src,
                                                const float* __restrict__ es,
                                                const float* __restrict__ ed,
                                                float* __restrict__ ev,
                                                float* __restrict__ s_,
                                                int H, int logH) {
    int wid = threadIdx.x >> 6;
    int lane = threadIdx.x & 63;
    int n = blockIdx.x * 4 + wid;
    if (n >= NN) return;
    int head = lane & (H - 1);
    int j = lane >> logH;
    int JP = 64 >> logH;
    int start = rowptr[n], end = rowptr[n + 1];
    float edv = ed[n * H + head];
    float m = -1e30f;
    for (int i = start + j; i < end; i += JP) {
        int src = csr_src[i];
        float v = es[src * H + head] + edv;
        v = v > 0.f ? v : 0.2f * v;
        m = fmaxf(m, v);
    }
#pragma unroll
    for (int off = 1; off < 64; off <<= 1)
        if (off >= H) m = fmaxf(m, __shfl_xor(m, off));
    float sum = 0.f;
    for (int i = start + j; i < end; i += JP) {
        int src = csr_src[i];
        float v = es[src * H + head] + edv;
        v = v > 0.f ? v : 0.2f * v;
        float p = __expf(v - m);
        ev[i * H + head] = p;
        sum += p;
    }
#pragma unroll
    for (int off = 1; off < 64; off <<= 1)
        if (off >= H) sum += __shfl_xor(sum, off);
    if (lane < H) s_[n * H + lane] = sum;
}

// ---------------- CSR aggregate (float4/thread, 8x unroll) + norm + bias + relu ----------------
template<int D, int H>
__global__ __launch_bounds__(256) void agg_csr4(const int* __restrict__ rowptr,
                                                const int* __restrict__ csr_src,
                                                const float* __restrict__ ev,
                                                const float* __restrict__ h,
                                                const float* __restrict__ s_,
                                                const float* __restrict__ b,
                                                float* __restrict__ out) {
    const int TPN = D / 4;
    const int NPB = 256 / TPN;
    int tid = threadIdx.x;
    int n = blockIdx.x * NPB + tid / TPN;
    if (n >= NN) return;
    int f0 = (tid % TPN) * 4;
    int head = f0 >> 6;
    int start = rowptr[n], end = rowptr[n + 1];
    float4 acc = make_float4(0.f, 0.f, 0.f, 0.f);
    int i = start;
    for (; i + 8 <= end; i += 8) {
        int s0 = csr_src[i + 0], s1 = csr_src[i + 1], s2 = csr_src[i + 2], s3 = csr_src[i + 3];
        int s4 = csr_src[i + 4], s5 = csr_src[i + 5], s6 = csr_src[i + 6], s7 = csr_src[i + 7];
        float p0 = ev[(i + 0) * H + head], p1 = ev[(i + 1) * H + head];
        float p2 = ev[(i + 2) * H + head], p3 = ev[(i + 3) * H + head];
        float p4 = ev[(i + 4) * H + head], p5 = ev[(i + 5) * H + head];
        float p6 = ev[(i + 6) * H + head], p7 = ev[(i + 7) * H + head];
        float4 h0 = *reinterpret_cast<const float4*>(h + (size_t)s0 * D + f0);
        float4 h1 = *reinterpret_cast<const float4*>(h + (size_t)s1 * D + f0);
        float4 h2 = *reinterpret_cast<const float4*>(h + (size_t)s2 * D + f0);
        float4 h3 = *reinterpret_cast<const float4*>(h + (size_t)s3 * D + f0);
        float4 h4 = *reinterpret_cast<const float4*>(h + (size_t)s4 * D + f0);
        float4 h5 = *reinterpret_cast<const float4*>(h + (size_t)s5 * D + f0);
        float4 h6 = *reinterpret_cast<const float4*>(h + (size_t)s6 * D + f0);
        float4 h7 = *reinterpret_cast<const float4*>(h + (size_t)s7 * D + f0);
        acc.x += p0 * h0.x + p1 * h1.x + p2 * h2.x + p3 * h3.x
               + p4 * h4.x + p5 * h5.x + p6 * h6.x + p7 * h7.x;
        acc.y += p0 * h0.y + p1 * h1.y + p2 * h2.y + p3 * h3.y
               + p4 * h4.y + p5 * h5.y + p6 * h6.y + p7 * h7.y;
        acc.z += p0 * h0.z + p1 * h1.z + p2 * h2.z + p3 * h3.z
               + p4 * h4.z + p5 * h5.z + p6 * h6.z + p7 * h7.z;
        acc.w += p0 * h0.w + p1 * h1.w + p2 * h2.w + p3 * h3.w
               + p4 * h4.w + p5 * h5.w + p6 * h6.w + p7 * h7.w;
    }
    for (; i < end; ++i) {
        int s0 = csr_src[i];
        float p0 = ev[i * H + head];
        float4 h0 = *reinterpret_cast<const float4*>(h + (size_t)s0 * D + f0);
        acc.x += p0 * h0.x; acc.y += p0 * h0.y; acc.z += p0 * h0.z; acc.w += p0 * h0.w;
    }
    float inv = 1.f / (s_[n * H + head] + 1e-16f);
    float4 bb = *reinterpret_cast<const float4*>(b + f0);
    float4 o;
    o.x = acc.x * inv + bb.x; o.y = acc.y * inv + bb.y;
    o.z = acc.z * inv + bb.z; o.w = acc.w * inv + bb.w;
    o.x = o.x > 0.f ? o.x : 0.f; o.y = o.y > 0.f ? o.y : 0.f;
    o.z = o.z > 0.f ? o.z : 0.f; o.w = o.w > 0.f ? o.w : 0.f;
    *reinterpret_cast<float4*>(out + (size_t)n * D + f0) = o;
}

// ---------------- final FC: out = h @ fc_W + fc_b ----------------
__global__ __launch_bounds__(256) void fc_kernel(const float* __restrict__ h,
                                                 const float* __restrict__ W,
                                                 const float* __restrict__ b,
                                                 float* __restrict__ out) {
    int idx = blockIdx.x * 256 + threadIdx.x;
    if (idx >= NN * 10) return;
    int n = idx / 10, j = idx - n * 10;
    float acc = b[j];
#pragma unroll
    for (int c = 0; c < 64; ++c) acc += h[n * 64 + c] * W[c * 10 + j];
    out[idx] = acc;
}

extern "C" void kernel_launch(void* const* d_in, const int* in_sizes, int n_in,
                              void* d_out, int out_size, void* d_ws, size_t ws_size,
                              hipStream_t stream) {
    const float* x   = (const float*)d_in[0];
    const int*   ei  = (const int*)d_in[1];
    const float* W1  = (const float*)d_in[2];
    const float* a1s = (const float*)d_in[3];
    const float* a1d = (const float*)d_in[4];
    const float* b1  = (const float*)d_in[5];
    const float* W2  = (const float*)d_in[6];
    const float* a2s = (const float*)d_in[7];
    const float* a2d = (const float*)d_in[8];
    const float* b2  = (const float*)d_in[9];
    const float* W3  = (const float*)d_in[10];
    const float* a3s = (const float*)d_in[11];
    const float* a3d = (const float*)d_in[12];
    const float* b3  = (const float*)d_in[13];
    const float* fcW = (const float*)d_in[14];
    const float* fcb = (const float*)d_in[15];
    float* out = (float*)d_out;

    float* A      = (float*)d_ws;                    // h buffer      [NN*256]
    float* B      = A + (size_t)NN * 256;            // activations   [NN*256]
    float* EV     = B + (size_t)NN * 256;            // p, CSR order  [E2]
    float* ES     = EV + (size_t)E2 * 4;             // [NN*4]
    float* ED     = ES + (size_t)NN * 4;             // [NN*4]
    float* S_     = ED + (size_t)NN * 4;             // [NN*4]
    int*   rowptr = (int*)(S_ + (size_t)NN * 4);     // [NN+1]
    int*   csrsrc = rowptr + (NN + 1);               // [E2]
    int*   deg    = csrsrc + E2;                     // [NN]
    int*   bsum   = deg + NN;                        // [SCAN_B]
    int*   boff   = bsum + 256;                      // [SCAN_B]
    int*   cursor = (int*)ES;                        // alias (pre-layer only)

    // ---- build CSR ----
    fill_i32<<<(NN + 255) / 256, 256, 0, stream>>>(deg, 1, NN);
    hist_dst<<<(NE + 255) / 256, 256, 0, stream>>>(ei, deg);
    block_sums<<<SCAN_B, 256, 0, stream>>>(deg, bsum);
    scan_bsums<<<1, 256, 0, stream>>>(bsum, boff);
    scan_final<<<SCAN_B, 256, 0, stream>>>(deg, boff, rowptr, cursor);
    scatter_csr<<<(E2 + 255) / 256, 256, 0, stream>>>(ei, cursor, csrsrc);

    auto run_layer = [&](const float* in, int K, int H, int logH,
                         const float* Wl, const float* as, const float* ad,
                         const float* bb, float* hbuf, float* obuf) {
        int D = H * 64;
        if (D == 256) {
            dim3 g((NN + GBM - 1) / GBM, D / GBN);
            gemm128<<<g, 256, 0, stream>>>(in, Wl, hbuf, NN, K, D);
        } else {
            dim3 g((NN + BM - 1) / BM, D / BN);
            gemm_f32<<<g, 256, 0, stream>>>(in, Wl, hbuf, NN, K, D);
        }
        escore<<<NN, D, 0, stream>>>(hbuf, as, ad, ES, ED, H);
        attn_csr<<<(NN + 3) / 4, 256, 0, stream>>>(rowptr, csrsrc, ES, ED, EV, S_, H, logH);
        if (D == 256) {
            agg_csr4<256, 4><<<(NN + 3) / 4, 256, 0, stream>>>(rowptr, csrsrc, EV, hbuf, S_, bb, obuf);
        } else {
            agg_csr4<64, 1><<<(NN + 15) / 16, 256, 0, stream>>>(rowptr, csrsrc, EV, hbuf, S_, bb, obuf);
        }
    };

    run_layer(x, IN_DIM, 4, 2, W1, a1s, a1d, b1, A, B);
    run_layer(B, 256,    4, 2, W2, a2s, a2d, b2, A, B);
    run_layer(B, 256,    1, 0, W3, a3s, a3d, b3, A, B);
    fc_kernel<<<(NN * 10 + 255) / 256, 256, 0, stream>>>(B, fcW, fcb, out);
}

// Round 5
// 630.164 us; speedup vs baseline: 3.6043x; 1.1534x over previous
//
#include <hip/hip_runtime.h>

#define NN 50000
#define NE 800000
#define E2 (NE + NN)   // edges + self loops
#define IN_DIM 128
#define SCAN_B 196     // ceil(NN/256)

typedef unsigned short u16;
typedef unsigned int u32;
typedef __attribute__((ext_vector_type(8))) short short8;
typedef __attribute__((ext_vector_type(4))) float f32x4;

__device__ inline u16 f2bf(float x) {
    u32 u = __float_as_uint(x);
    u32 r = (u + 0x7fff + ((u >> 16) & 1)) >> 16;   // RNE
    return (u16)r;
}
__device__ inline float bf2f(u16 h) { return __uint_as_float(((u32)h) << 16); }

// ---------------- fills ----------------
__global__ __launch_bounds__(256) void fill_i32(int* __restrict__ p, int v, int n) {
    int i = blockIdx.x * 256 + threadIdx.x;
    if (i < n) p[i] = v;
}

// ---------------- CSR build ----------------
__global__ __launch_bounds__(256) void hist_dst(const int* __restrict__ ei, int* __restrict__ deg) {
    int e = blockIdx.x * 256 + threadIdx.x;
    if (e < NE) atomicAdd(&deg[ei[NE + e]], 1);
}

__global__ __launch_bounds__(256) void block_sums(const int* __restrict__ deg, int* __restrict__ bsum) {
    int b = blockIdx.x;
    int i = b * 256 + threadIdx.x;
    int v = (i < NN) ? deg[i] : 0;
#pragma unroll
    for (int off = 32; off; off >>= 1) v += __shfl_down(v, off);
    __shared__ int ws[4];
    if ((threadIdx.x & 63) == 0) ws[threadIdx.x >> 6] = v;
    __syncthreads();
    if (threadIdx.x == 0) bsum[b] = ws[0] + ws[1] + ws[2] + ws[3];
}

__global__ __launch_bounds__(256) void scan_bsums(const int* __restrict__ bsum, int* __restrict__ boff) {
    __shared__ int s[256];
    int t = threadIdx.x;
    int v = (t < SCAN_B) ? bsum[t] : 0;
    s[t] = v;
    __syncthreads();
    for (int off = 1; off < 256; off <<= 1) {
        int u = (t >= off) ? s[t - off] : 0;
        __syncthreads();
        s[t] += u;
        __syncthreads();
    }
    if (t < SCAN_B) boff[t] = s[t] - v;
}

__global__ __launch_bounds__(256) void scan_final(const int* __restrict__ deg,
                                                  const int* __restrict__ boff,
                                                  int* __restrict__ rowptr,
                                                  int* __restrict__ cursor) {
    int b = blockIdx.x;
    int t = threadIdx.x;
    int i = b * 256 + t;
    int v = (i < NN) ? deg[i] : 0;
    __shared__ int s[256];
    s[t] = v;
    __syncthreads();
    for (int off = 1; off < 256; off <<= 1) {
        int u = (t >= off) ? s[t - off] : 0;
        __syncthreads();
        s[t] += u;
        __syncthreads();
    }
    int excl = s[t] - v + boff[b];
    if (i < NN) { rowptr[i] = excl; cursor[i] = excl; }
    if (i == NN - 1) rowptr[NN] = excl + v;
}

__global__ __launch_bounds__(256) void scatter_csr(const int* __restrict__ ei,
                                                   int* __restrict__ cursor,
                                                   int* __restrict__ csr_src) {
    int e = blockIdx.x * 256 + threadIdx.x;
    if (e >= E2) return;
    int s, d;
    if (e < NE) { s = ei[e]; d = ei[NE + e]; } else { s = d = e - NE; }
    int pos = atomicAdd(&cursor[d], 1);
    csr_src[pos] = s;
}

// ---------------- split-bf16 converters ----------------
// X f32 [M][K] -> Xh, Xl bf16 [M][K]   (vectorized, total4 = M*K/4)
__global__ __launch_bounds__(256) void xconv(const float* __restrict__ X,
                                             u16* __restrict__ Xh, u16* __restrict__ Xl,
                                             int total4) {
    int i = blockIdx.x * 256 + threadIdx.x;
    if (i >= total4) return;
    float4 v = reinterpret_cast<const float4*>(X)[i];
    ushort4 h, l;
    h.x = f2bf(v.x); l.x = f2bf(v.x - bf2f(h.x));
    h.y = f2bf(v.y); l.y = f2bf(v.y - bf2f(h.y));
    h.z = f2bf(v.z); l.z = f2bf(v.z - bf2f(h.z));
    h.w = f2bf(v.w); l.w = f2bf(v.w - bf2f(h.w));
    reinterpret_cast<ushort4*>(Xh)[i] = h;
    reinterpret_cast<ushort4*>(Xl)[i] = l;
}

// W f32 [K][N] -> Wt_h, Wt_l bf16 [N][K]  (transpose + split; small)
__global__ __launch_bounds__(256) void wconv(const float* __restrict__ W,
                                             u16* __restrict__ Wh, u16* __restrict__ Wl,
                                             int K, int N) {
    int idx = blockIdx.x * 256 + threadIdx.x;
    if (idx >= K * N) return;
    int k = idx / N, n = idx - k * N;
    float w = W[idx];
    u16 hi = f2bf(w);
    Wh[(size_t)n * K + k] = hi;
    Wl[(size_t)n * K + k] = f2bf(w - bf2f(hi));
}

// ---------------- split-bf16 MFMA GEMM ----------------
// C[M,N] = (Ah+Al)[M,K] @ (Wh+Wl)^T[N,K]^T   via 3 bf16 MFMAs per tile
// BM=128, BN in {128,64}, BK=32, 4 waves (2x2), wave tile 64 x BN/2
template<int BN, int KK>
__global__ __launch_bounds__(256) void gemm_mfma(const u16* __restrict__ Ah,
                                                 const u16* __restrict__ Al,
                                                 const u16* __restrict__ Wh,
                                                 const u16* __restrict__ Wl,
                                                 float* __restrict__ C,
                                                 int M, int N) {
    const int BM = 128, BK = 32, LDT = BK + 8;   // stride 40 u16 = 80B (16B-aligned, balanced banks)
    __shared__ u16 Ahs[BM][LDT], Als[BM][LDT];
    __shared__ u16 Bhs[BN][LDT], Bls[BN][LDT];
    const int FRN = BN / 32;                      // N-fragments per wave
    int tid = threadIdx.x;
    int lane = tid & 63, wid = tid >> 6;
    int wm = wid >> 1, wn = wid & 1;
    int row0 = blockIdx.x * BM, col0 = blockIdx.y * BN;
    int l15 = lane & 15, lg = lane >> 4;

    f32x4 acc[4][FRN];
#pragma unroll
    for (int i = 0; i < 4; ++i)
#pragma unroll
        for (int j = 0; j < FRN; ++j) acc[i][j] = (f32x4){0.f, 0.f, 0.f, 0.f};

    for (int ko = 0; ko < KK; ko += BK) {
        __syncthreads();
        // stage A hi/lo: 512 16B-chunks per buffer, 2 per thread
#pragma unroll
        for (int cc = 0; cc < 2; ++cc) {
            int c = tid * 2 + cc;
            int r = c >> 2, sub = (c & 3) * 8;
            int gr = row0 + r;
            uint4 vh = make_uint4(0, 0, 0, 0), vl = vh;
            if (gr < M) {
                vh = *reinterpret_cast<const uint4*>(Ah + (size_t)gr * KK + ko + sub);
                vl = *reinterpret_cast<const uint4*>(Al + (size_t)gr * KK + ko + sub);
            }
            *reinterpret_cast<uint4*>(&Ahs[r][sub]) = vh;
            *reinterpret_cast<uint4*>(&Als[r][sub]) = vl;
        }
        // stage B hi/lo (cols always in range: N multiple of BN)
#pragma unroll
        for (int c = tid; c < BN * 4; c += 256) {
            int r = c >> 2, sub = (c & 3) * 8;
            int gc = col0 + r;
            uint4 vh = *reinterpret_cast<const uint4*>(Wh + (size_t)gc * KK + ko + sub);
            uint4 vl = *reinterpret_cast<const uint4*>(Wl + (size_t)gc * KK + ko + sub);
            *reinterpret_cast<uint4*>(&Bhs[r][sub]) = vh;
            *reinterpret_cast<uint4*>(&Bls[r][sub]) = vl;
        }
        __syncthreads();
        short8 ah[4], al[4], bh[FRN], bl[FRN];
#pragma unroll
        for (int i = 0; i < 4; ++i) {
            int r = wm * 64 + i * 16 + l15;
            ah[i] = *reinterpret_cast<const short8*>(&Ahs[r][lg * 8]);
            al[i] = *reinterpret_cast<const short8*>(&Als[r][lg * 8]);
        }
#pragma unroll
        for (int j = 0; j < FRN; ++j) {
            int cc = wn * (BN / 2) + j * 16 + l15;
            bh[j] = *reinterpret_cast<const short8*>(&Bhs[cc][lg * 8]);
            bl[j] = *reinterpret_cast<const short8*>(&Bls[cc][lg * 8]);
        }
#pragma unroll
        for (int i = 0; i < 4; ++i)
#pragma unroll
            for (int j = 0; j < FRN; ++j) {
                acc[i][j] = __builtin_amdgcn_mfma_f32_16x16x32_bf16(ah[i], bh[j], acc[i][j], 0, 0, 0);
                acc[i][j] = __builtin_amdgcn_mfma_f32_16x16x32_bf16(ah[i], bl[j], acc[i][j], 0, 0, 0);
                acc[i][j] = __builtin_amdgcn_mfma_f32_16x16x32_bf16(al[i], bh[j], acc[i][j], 0, 0, 0);
            }
    }
    // epilogue: D row = (lane>>4)*4 + reg, col = lane&15  (m89-verified)
#pragma unroll
    for (int i = 0; i < 4; ++i)
#pragma unroll
        for (int rr = 0; rr < 4; ++rr) {
            int gr = row0 + wm * 64 + i * 16 + lg * 4 + rr;
            if (gr < M) {
#pragma unroll
                for (int j = 0; j < FRN; ++j)
                    C[(size_t)gr * N + col0 + wn * (BN / 2) + j * 16 + l15] = acc[i][j][rr];
            }
        }
}

// ---------------- attention scores per node/head ----------------
__global__ void escore(const float* __restrict__ h, const float* __restrict__ as,
                       const float* __restrict__ ad, float* __restrict__ es,
                       float* __restrict__ ed, int H) {
    int n = blockIdx.x;
    int t = threadIdx.x;
    int D = blockDim.x;
    float hv = h[(size_t)n * D + t];
    float vs = hv * as[t];
    float vd = hv * ad[t];
#pragma unroll
    for (int off = 32; off; off >>= 1) {
        vs += __shfl_down(vs, off);
        vd += __shfl_down(vd, off);
    }
    if ((t & 63) == 0) {
        int head = t >> 6;
        es[n * H + head] = vs;
        ed[n * H + head] = vd;
    }
}

// ---------------- fused per-node softmax over incoming edges (CSR) ----------------
__global__ __launch_bounds__(256) void attn_csr(const int* __restrict__ rowptr,
                                                const int* __restrict__ csr_src,
                                                const float* __restrict__ es,
                                                const float* __restrict__ ed,
                                                float* __restrict__ ev,
                                                float* __restrict__ s_,
                                                int H, int logH) {
    int wid = threadIdx.x >> 6;
    int lane = threadIdx.x & 63;
    int n = blockIdx.x * 4 + wid;
    if (n >= NN) return;
    int head = lane & (H - 1);
    int j = lane >> logH;
    int JP = 64 >> logH;
    int start = rowptr[n], end = rowptr[n + 1];
    float edv = ed[n * H + head];
    float m = -1e30f;
    for (int i = start + j; i < end; i += JP) {
        int src = csr_src[i];
        float v = es[src * H + head] + edv;
        v = v > 0.f ? v : 0.2f * v;
        m = fmaxf(m, v);
    }
#pragma unroll
    for (int off = 1; off < 64; off <<= 1)
        if (off >= H) m = fmaxf(m, __shfl_xor(m, off));
    float sum = 0.f;
    for (int i = start + j; i < end; i += JP) {
        int src = csr_src[i];
        float v = es[src * H + head] + edv;
        v = v > 0.f ? v : 0.2f * v;
        float p = __expf(v - m);
        ev[i * H + head] = p;
        sum += p;
    }
#pragma unroll
    for (int off = 1; off < 64; off <<= 1)
        if (off >= H) sum += __shfl_xor(sum, off);
    if (lane < H) s_[n * H + lane] = sum;
}

// ---------------- CSR aggregate + norm + bias + relu -> split-bf16 output ----------------
template<int D, int H>
__global__ __launch_bounds__(256) void agg_csr4(const int* __restrict__ rowptr,
                                                const int* __restrict__ csr_src,
                                                const float* __restrict__ ev,
                                                const float* __restrict__ h,
                                                const float* __restrict__ s_,
                                                const float* __restrict__ b,
                                                u16* __restrict__ Oh,
                                                u16* __restrict__ Ol) {
    const int TPN = D / 4;
    const int NPB = 256 / TPN;
    int tid = threadIdx.x;
    int n = blockIdx.x * NPB + tid / TPN;
    if (n >= NN) return;
    int f0 = (tid % TPN) * 4;
    int head = f0 >> 6;
    int start = rowptr[n], end = rowptr[n + 1];
    float4 acc = make_float4(0.f, 0.f, 0.f, 0.f);
    int i = start;
    for (; i + 8 <= end; i += 8) {
        int s0 = csr_src[i + 0], s1 = csr_src[i + 1], s2 = csr_src[i + 2], s3 = csr_src[i + 3];
        int s4 = csr_src[i + 4], s5 = csr_src[i + 5], s6 = csr_src[i + 6], s7 = csr_src[i + 7];
        float p0 = ev[(i + 0) * H + head], p1 = ev[(i + 1) * H + head];
        float p2 = ev[(i + 2) * H + head], p3 = ev[(i + 3) * H + head];
        float p4 = ev[(i + 4) * H + head], p5 = ev[(i + 5) * H + head];
        float p6 = ev[(i + 6) * H + head], p7 = ev[(i + 7) * H + head];
        float4 h0 = *reinterpret_cast<const float4*>(h + (size_t)s0 * D + f0);
        float4 h1 = *reinterpret_cast<const float4*>(h + (size_t)s1 * D + f0);
        float4 h2 = *reinterpret_cast<const float4*>(h + (size_t)s2 * D + f0);
        float4 h3 = *reinterpret_cast<const float4*>(h + (size_t)s3 * D + f0);
        float4 h4 = *reinterpret_cast<const float4*>(h + (size_t)s4 * D + f0);
        float4 h5 = *reinterpret_cast<const float4*>(h + (size_t)s5 * D + f0);
        float4 h6 = *reinterpret_cast<const float4*>(h + (size_t)s6 * D + f0);
        float4 h7 = *reinterpret_cast<const float4*>(h + (size_t)s7 * D + f0);
        acc.x += p0 * h0.x + p1 * h1.x + p2 * h2.x + p3 * h3.x
               + p4 * h4.x + p5 * h5.x + p6 * h6.x + p7 * h7.x;
        acc.y += p0 * h0.y + p1 * h1.y + p2 * h2.y + p3 * h3.y
               + p4 * h4.y + p5 * h5.y + p6 * h6.y + p7 * h7.y;
        acc.z += p0 * h0.z + p1 * h1.z + p2 * h2.z + p3 * h3.z
               + p4 * h4.z + p5 * h5.z + p6 * h6.z + p7 * h7.z;
        acc.w += p0 * h0.w + p1 * h1.w + p2 * h2.w + p3 * h3.w
               + p4 * h4.w + p5 * h5.w + p6 * h6.w + p7 * h7.w;
    }
    for (; i < end; ++i) {
        int s0 = csr_src[i];
        float p0 = ev[i * H + head];
        float4 h0 = *reinterpret_cast<const float4*>(h + (size_t)s0 * D + f0);
        acc.x += p0 * h0.x; acc.y += p0 * h0.y; acc.z += p0 * h0.z; acc.w += p0 * h0.w;
    }
    float inv = 1.f / (s_[n * H + head] + 1e-16f);
    float4 bb = *reinterpret_cast<const float4*>(b + f0);
    float4 o;
    o.x = acc.x * inv + bb.x; o.y = acc.y * inv + bb.y;
    o.z = acc.z * inv + bb.z; o.w = acc.w * inv + bb.w;
    o.x = o.x > 0.f ? o.x : 0.f; o.y = o.y > 0.f ? o.y : 0.f;
    o.z = o.z > 0.f ? o.z : 0.f; o.w = o.w > 0.f ? o.w : 0.f;
    ushort4 hv, lv;
    hv.x = f2bf(o.x); lv.x = f2bf(o.x - bf2f(hv.x));
    hv.y = f2bf(o.y); lv.y = f2bf(o.y - bf2f(hv.y));
    hv.z = f2bf(o.z); lv.z = f2bf(o.z - bf2f(hv.z));
    hv.w = f2bf(o.w); lv.w = f2bf(o.w - bf2f(hv.w));
    *reinterpret_cast<ushort4*>(Oh + (size_t)n * D + f0) = hv;
    *reinterpret_cast<ushort4*>(Ol + (size_t)n * D + f0) = lv;
}

// ---------------- final FC: out = h @ fc_W + fc_b (h from split-bf16 pair) ----------------
__global__ __launch_bounds__(256) void fc_kernel(const u16* __restrict__ Hh,
                                                 const u16* __restrict__ Hl,
                                                 const float* __restrict__ W,
                                                 const float* __restrict__ b,
                                                 float* __restrict__ out) {
    int idx = blockIdx.x * 256 + threadIdx.x;
    if (idx >= NN * 10) return;
    int n = idx / 10, j = idx - n * 10;
    float acc = b[j];
#pragma unroll
    for (int c = 0; c < 64; ++c) {
        float hv = bf2f(Hh[n * 64 + c]) + bf2f(Hl[n * 64 + c]);
        acc += hv * W[c * 10 + j];
    }
    out[idx] = acc;
}

extern "C" void kernel_launch(void* const* d_in, const int* in_sizes, int n_in,
                              void* d_out, int out_size, void* d_ws, size_t ws_size,
                              hipStream_t stream) {
    const float* x   = (const float*)d_in[0];
    const int*   ei  = (const int*)d_in[1];
    const float* W1  = (const float*)d_in[2];
    const float* a1s = (const float*)d_in[3];
    const float* a1d = (const float*)d_in[4];
    const float* b1  = (const float*)d_in[5];
    const float* W2  = (const float*)d_in[6];
    const float* a2s = (const float*)d_in[7];
    const float* a2d = (const float*)d_in[8];
    const float* b2  = (const float*)d_in[9];
    const float* W3  = (const float*)d_in[10];
    const float* a3s = (const float*)d_in[11];
    const float* a3d = (const float*)d_in[12];
    const float* b3  = (const float*)d_in[13];
    const float* fcW = (const float*)d_in[14];
    const float* fcb = (const float*)d_in[15];
    float* out = (float*)d_out;

    // ---- workspace layout ----
    char* wp = (char*)d_ws;
    float* h   = (float*)wp;  wp += (size_t)NN * 256 * 4;     // GEMM output, f32   51.2MB
    u16* Ph    = (u16*)wp;    wp += (size_t)NN * 256 * 2;     // activation hi      25.6MB
    u16* Pl    = (u16*)wp;    wp += (size_t)NN * 256 * 2;     // activation lo      25.6MB
    u16* Xh    = (u16*)wp;    wp += (size_t)NN * 128 * 2;     // x hi (EV aliases)  12.8MB
    u16* Xl    = (u16*)wp;    wp += (size_t)NN * 128 * 2;     // x lo               12.8MB
    float* EV  = (float*)Xh;                                   // alias: dead after L1 GEMM
    float* ES  = (float*)wp;  wp += (size_t)NN * 4 * 4;
    float* ED  = (float*)wp;  wp += (size_t)NN * 4 * 4;
    float* S_  = (float*)wp;  wp += (size_t)NN * 4 * 4;
    u16* Wth   = (u16*)wp;    wp += 256 * 256 * 2;
    u16* Wtl   = (u16*)wp;    wp += 256 * 256 * 2;
    int* rowptr = (int*)wp;   wp += (NN + 1) * 4;
    int* csrsrc = (int*)wp;   wp += (size_t)E2 * 4;
    int* deg    = (int*)wp;   wp += NN * 4;
    int* bsum   = (int*)wp;   wp += 256 * 4;
    int* boff   = (int*)wp;   wp += 256 * 4;
    int* cursor = (int*)ES;                                    // alias: used pre-escore only

    // ---- build CSR ----
    fill_i32<<<(NN + 255) / 256, 256, 0, stream>>>(deg, 1, NN);
    hist_dst<<<(NE + 255) / 256, 256, 0, stream>>>(ei, deg);
    block_sums<<<SCAN_B, 256, 0, stream>>>(deg, bsum);
    scan_bsums<<<1, 256, 0, stream>>>(bsum, boff);
    scan_final<<<SCAN_B, 256, 0, stream>>>(deg, boff, rowptr, cursor);
    scatter_csr<<<(E2 + 255) / 256, 256, 0, stream>>>(ei, cursor, csrsrc);

    // ---- split input x ----
    xconv<<<(NN * IN_DIM / 4 + 255) / 256, 256, 0, stream>>>(x, Xh, Xl, NN * IN_DIM / 4);

    const int MT = (NN + 127) / 128;  // 391 M-tiles

    // ======== layer 1: K=128, D=256, H=4 ========
    wconv<<<(IN_DIM * 256 + 255) / 256, 256, 0, stream>>>(W1, Wth, Wtl, IN_DIM, 256);
    gemm_mfma<128, 128><<<dim3(MT, 2), 256, 0, stream>>>(Xh, Xl, Wth, Wtl, h, NN, 256);
    escore<<<NN, 256, 0, stream>>>(h, a1s, a1d, ES, ED, 4);
    attn_csr<<<(NN + 3) / 4, 256, 0, stream>>>(rowptr, csrsrc, ES, ED, EV, S_, 4, 2);
    agg_csr4<256, 4><<<(NN + 3) / 4, 256, 0, stream>>>(rowptr, csrsrc, EV, h, S_, b1, Ph, Pl);

    // ======== layer 2: K=256, D=256, H=4 ========
    wconv<<<(256 * 256 + 255) / 256, 256, 0, stream>>>(W2, Wth, Wtl, 256, 256);
    gemm_mfma<128, 256><<<dim3(MT, 2), 256, 0, stream>>>(Ph, Pl, Wth, Wtl, h, NN, 256);
    escore<<<NN, 256, 0, stream>>>(h, a2s, a2d, ES, ED, 4);
    attn_csr<<<(NN + 3) / 4, 256, 0, stream>>>(rowptr, csrsrc, ES, ED, EV, S_, 4, 2);
    agg_csr4<256, 4><<<(NN + 3) / 4, 256, 0, stream>>>(rowptr, csrsrc, EV, h, S_, b2, Ph, Pl);

    // ======== layer 3: K=256, D=64, H=1 ========
    wconv<<<(256 * 64 + 255) / 256, 256, 0, stream>>>(W3, Wth, Wtl, 256, 64);
    gemm_mfma<64, 256><<<dim3(MT, 1), 256, 0, stream>>>(Ph, Pl, Wth, Wtl, h, NN, 64);
    escore<<<NN, 64, 0, stream>>>(h, a3s, a3d, ES, ED, 1);
    attn_csr<<<(NN + 3) / 4, 256, 0, stream>>>(rowptr, csrsrc, ES, ED, EV, S_, 1, 0);
    agg_csr4<64, 1><<<(NN + 15) / 16, 256, 0, stream>>>(rowptr, csrsrc, EV, h, S_, b3, Ph, Pl);

    // ======== classifier ========
    fc_kernel<<<(NN * 10 + 255) / 256, 256, 0, stream>>>(Ph, Pl, fcW, fcb, out);
}

// Round 6
// 609.316 us; speedup vs baseline: 3.7276x; 1.0342x over previous
//
#include <hip/hip_runtime.h>

#define NN 50000
#define NE 800000
#define E2 (NE + NN)   // edges + self loops
#define IN_DIM 128
#define SCAN_B 196     // ceil(NN/256)

typedef unsigned short u16;
typedef unsigned int u32;
typedef __attribute__((ext_vector_type(8))) short short8;
typedef __attribute__((ext_vector_type(4))) float f32x4;

__device__ inline u16 f2bf(float x) {
    u32 u = __float_as_uint(x);
    u32 r = (u + 0x7fff + ((u >> 16) & 1)) >> 16;   // RNE
    return (u16)r;
}
__device__ inline float bf2f(u16 h) { return __uint_as_float(((u32)h) << 16); }

// ---------------- fills ----------------
__global__ __launch_bounds__(256) void fill_i32(int* __restrict__ p, int v, int n) {
    int i = blockIdx.x * 256 + threadIdx.x;
    if (i < n) p[i] = v;
}

// ---------------- CSR build ----------------
__global__ __launch_bounds__(256) void hist_dst(const int* __restrict__ ei, int* __restrict__ deg) {
    int e = blockIdx.x * 256 + threadIdx.x;
    if (e < NE) atomicAdd(&deg[ei[NE + e]], 1);
}

__global__ __launch_bounds__(256) void block_sums(const int* __restrict__ deg, int* __restrict__ bsum) {
    int b = blockIdx.x;
    int i = b * 256 + threadIdx.x;
    int v = (i < NN) ? deg[i] : 0;
#pragma unroll
    for (int off = 32; off; off >>= 1) v += __shfl_down(v, off);
    __shared__ int ws[4];
    if ((threadIdx.x & 63) == 0) ws[threadIdx.x >> 6] = v;
    __syncthreads();
    if (threadIdx.x == 0) bsum[b] = ws[0] + ws[1] + ws[2] + ws[3];
}

__global__ __launch_bounds__(256) void scan_bsums(const int* __restrict__ bsum, int* __restrict__ boff) {
    __shared__ int s[256];
    int t = threadIdx.x;
    int v = (t < SCAN_B) ? bsum[t] : 0;
    s[t] = v;
    __syncthreads();
    for (int off = 1; off < 256; off <<= 1) {
        int u = (t >= off) ? s[t - off] : 0;
        __syncthreads();
        s[t] += u;
        __syncthreads();
    }
    if (t < SCAN_B) boff[t] = s[t] - v;
}

__global__ __launch_bounds__(256) void scan_final(const int* __restrict__ deg,
                                                  const int* __restrict__ boff,
                                                  int* __restrict__ rowptr,
                                                  int* __restrict__ cursor) {
    int b = blockIdx.x;
    int t = threadIdx.x;
    int i = b * 256 + t;
    int v = (i < NN) ? deg[i] : 0;
    __shared__ int s[256];
    s[t] = v;
    __syncthreads();
    for (int off = 1; off < 256; off <<= 1) {
        int u = (t >= off) ? s[t - off] : 0;
        __syncthreads();
        s[t] += u;
        __syncthreads();
    }
    int excl = s[t] - v + boff[b];
    if (i < NN) { rowptr[i] = excl; cursor[i] = excl; }
    if (i == NN - 1) rowptr[NN] = excl + v;
}

__global__ __launch_bounds__(256) void scatter_csr(const int* __restrict__ ei,
                                                   int* __restrict__ cursor,
                                                   int* __restrict__ csr_src) {
    int e = blockIdx.x * 256 + threadIdx.x;
    if (e >= E2) return;
    int s, d;
    if (e < NE) { s = ei[e]; d = ei[NE + e]; } else { s = d = e - NE; }
    int pos = atomicAdd(&cursor[d], 1);
    csr_src[pos] = s;
}

// ---------------- split-bf16 converters ----------------
__global__ __launch_bounds__(256) void xconv(const float* __restrict__ X,
                                             u16* __restrict__ Xh, u16* __restrict__ Xl,
                                             int total4) {
    int i = blockIdx.x * 256 + threadIdx.x;
    if (i >= total4) return;
    float4 v = reinterpret_cast<const float4*>(X)[i];
    ushort4 h, l;
    h.x = f2bf(v.x); l.x = f2bf(v.x - bf2f(h.x));
    h.y = f2bf(v.y); l.y = f2bf(v.y - bf2f(h.y));
    h.z = f2bf(v.z); l.z = f2bf(v.z - bf2f(h.z));
    h.w = f2bf(v.w); l.w = f2bf(v.w - bf2f(h.w));
    reinterpret_cast<ushort4*>(Xh)[i] = h;
    reinterpret_cast<ushort4*>(Xl)[i] = l;
}

__global__ __launch_bounds__(256) void wconv(const float* __restrict__ W,
                                             u16* __restrict__ Wh, u16* __restrict__ Wl,
                                             int K, int N) {
    int idx = blockIdx.x * 256 + threadIdx.x;
    if (idx >= K * N) return;
    int k = idx / N, n = idx - k * N;
    float w = W[idx];
    u16 hi = f2bf(w);
    Wh[(size_t)n * K + k] = hi;
    Wl[(size_t)n * K + k] = f2bf(w - bf2f(hi));
}

// ---------------- split-bf16 MFMA GEMM (reg-staged prefetch) ----------------
template<int BN, int KK>
__global__ __launch_bounds__(256) void gemm_mfma(const u16* __restrict__ Ah,
                                                 const u16* __restrict__ Al,
                                                 const u16* __restrict__ Wh,
                                                 const u16* __restrict__ Wl,
                                                 float* __restrict__ C,
                                                 int M, int N) {
    const int BM = 128, BK = 32, LDT = BK + 8;
    __shared__ u16 Ahs[BM][LDT], Als[BM][LDT];
    __shared__ u16 Bhs[BN][LDT], Bls[BN][LDT];
    const int FRN = BN / 32;
    const int NB = BN * 4 / 256;                  // B 16B-chunks per thread
    int tid = threadIdx.x;
    int lane = tid & 63, wid = tid >> 6;
    int wm = wid >> 1, wn = wid & 1;
    int row0 = blockIdx.x * BM, col0 = blockIdx.y * BN;
    int l15 = lane & 15, lg = lane >> 4;

    // staging coords: A = 2 chunks per thread (same row, two 8-elem subs)
    int c0 = tid * 2;
    int r_a = c0 >> 2, sub_a0 = (c0 & 3) * 8, sub_a1 = ((c0 + 1) & 3) * 8;
    int gr_a = row0 + r_a;

    uint4 avh[2], avl[2], bvh[NB], bvl[NB];
    auto loadA = [&](int ko) {
        if (gr_a < M) {
            avh[0] = *reinterpret_cast<const uint4*>(Ah + (size_t)gr_a * KK + ko + sub_a0);
            avl[0] = *reinterpret_cast<const uint4*>(Al + (size_t)gr_a * KK + ko + sub_a0);
            avh[1] = *reinterpret_cast<const uint4*>(Ah + (size_t)gr_a * KK + ko + sub_a1);
            avl[1] = *reinterpret_cast<const uint4*>(Al + (size_t)gr_a * KK + ko + sub_a1);
        } else {
            avh[0] = avh[1] = avl[0] = avl[1] = make_uint4(0, 0, 0, 0);
        }
    };
    auto loadB = [&](int ko) {
#pragma unroll
        for (int q = 0; q < NB; ++q) {
            int c = tid + q * 256;
            int r = c >> 2, sub = (c & 3) * 8;
            int gc = col0 + r;
            bvh[q] = *reinterpret_cast<const uint4*>(Wh + (size_t)gc * KK + ko + sub);
            bvl[q] = *reinterpret_cast<const uint4*>(Wl + (size_t)gc * KK + ko + sub);
        }
    };

    f32x4 acc[4][FRN];
#pragma unroll
    for (int i = 0; i < 4; ++i)
#pragma unroll
        for (int j = 0; j < FRN; ++j) acc[i][j] = (f32x4){0.f, 0.f, 0.f, 0.f};

    loadA(0); loadB(0);
    for (int ko = 0; ko < KK; ko += BK) {
        __syncthreads();
        *reinterpret_cast<uint4*>(&Ahs[r_a][sub_a0]) = avh[0];
        *reinterpret_cast<uint4*>(&Als[r_a][sub_a0]) = avl[0];
        *reinterpret_cast<uint4*>(&Ahs[r_a][sub_a1]) = avh[1];
        *reinterpret_cast<uint4*>(&Als[r_a][sub_a1]) = avl[1];
#pragma unroll
        for (int q = 0; q < NB; ++q) {
            int c = tid + q * 256;
            int r = c >> 2, sub = (c & 3) * 8;
            *reinterpret_cast<uint4*>(&Bhs[r][sub]) = bvh[q];
            *reinterpret_cast<uint4*>(&Bls[r][sub]) = bvl[q];
        }
        __syncthreads();
        if (ko + BK < KK) { loadA(ko + BK); loadB(ko + BK); }  // prefetch overlaps MFMA
        short8 ah[4], al[4], bh[FRN], bl[FRN];
#pragma unroll
        for (int i = 0; i < 4; ++i) {
            int r = wm * 64 + i * 16 + l15;
            ah[i] = *reinterpret_cast<const short8*>(&Ahs[r][lg * 8]);
            al[i] = *reinterpret_cast<const short8*>(&Als[r][lg * 8]);
        }
#pragma unroll
        for (int j = 0; j < FRN; ++j) {
            int cc = wn * (BN / 2) + j * 16 + l15;
            bh[j] = *reinterpret_cast<const short8*>(&Bhs[cc][lg * 8]);
            bl[j] = *reinterpret_cast<const short8*>(&Bls[cc][lg * 8]);
        }
#pragma unroll
        for (int i = 0; i < 4; ++i)
#pragma unroll
            for (int j = 0; j < FRN; ++j) {
                acc[i][j] = __builtin_amdgcn_mfma_f32_16x16x32_bf16(ah[i], bh[j], acc[i][j], 0, 0, 0);
                acc[i][j] = __builtin_amdgcn_mfma_f32_16x16x32_bf16(ah[i], bl[j], acc[i][j], 0, 0, 0);
                acc[i][j] = __builtin_amdgcn_mfma_f32_16x16x32_bf16(al[i], bh[j], acc[i][j], 0, 0, 0);
            }
    }
#pragma unroll
    for (int i = 0; i < 4; ++i)
#pragma unroll
        for (int rr = 0; rr < 4; ++rr) {
            int gr = row0 + wm * 64 + i * 16 + lg * 4 + rr;
            if (gr < M) {
#pragma unroll
                for (int j = 0; j < FRN; ++j)
                    C[(size_t)gr * N + col0 + wn * (BN / 2) + j * 16 + l15] = acc[i][j][rr];
            }
        }
}

// ---------------- attention scores per node/head ----------------
__global__ void escore(const float* __restrict__ h, const float* __restrict__ as,
                       const float* __restrict__ ad, float* __restrict__ es,
                       float* __restrict__ ed, int H) {
    int n = blockIdx.x;
    int t = threadIdx.x;
    int D = blockDim.x;
    float hv = h[(size_t)n * D + t];
    float vs = hv * as[t];
    float vd = hv * ad[t];
#pragma unroll
    for (int off = 32; off; off >>= 1) {
        vs += __shfl_down(vs, off);
        vd += __shfl_down(vd, off);
    }
    if ((t & 63) == 0) {
        int head = t >> 6;
        es[n * H + head] = vs;
        ed[n * H + head] = vd;
    }
}

// ---------------- FUSED softmax + aggregate + norm + bias + relu -> split-bf16 ----------------
// TPN = D/4 lanes per node (64 for D=256, 16 for D=64); group handles softmax AND gather.
template<int D, int H>
__global__ __launch_bounds__(256) void agg_fused(const int* __restrict__ rowptr,
                                                 const int* __restrict__ csr_src,
                                                 const float* __restrict__ es,
                                                 const float* __restrict__ ed,
                                                 const float* __restrict__ h,
                                                 const float* __restrict__ b,
                                                 u16* __restrict__ Oh,
                                                 u16* __restrict__ Ol) {
    const int TPN = D / 4;
    const int NPB = 256 / TPN;
    const int logH = (H == 4) ? 2 : 0;
    int tid = threadIdx.x;
    int n = blockIdx.x * NPB + tid / TPN;
    if (n >= NN) return;
    int gl = tid % TPN;
    int start = rowptr[n], end = rowptr[n + 1];

    // ---- phase A: per-head max over edges (edge-parallel, JP=16 slots) ----
    int headA = gl & (H - 1);
    const int JP = TPN >> logH;
    float edvA = ed[n * H + headA];
    float m = -1e30f;
    for (int i = start + (gl >> logH); i < end; i += JP) {
        int src = csr_src[i];
        float v = es[src * H + headA] + edvA;
        v = v > 0.f ? v : 0.2f * v;
        m = fmaxf(m, v);
    }
#pragma unroll
    for (int off = H; off < TPN; off <<= 1)
        m = fmaxf(m, __shfl_xor(m, off));

    // ---- phase B: serial edge loop, p computed inline, gather h ----
    int f0 = gl * 4;
    int hb = f0 >> 6;               // this lane's head in feature space
    float mB;
    if (D == 256) mB = __shfl(m, hb);   // group == wave; lane hb holds head hb's max
    else          mB = m;                // H==1: uniform within 16-lane group
    float edv = ed[n * H + hb];
    float sump = 0.f;
    float4 acc = make_float4(0.f, 0.f, 0.f, 0.f);
    int i = start;
    for (; i + 8 <= end; i += 8) {
        int s0 = csr_src[i + 0], s1 = csr_src[i + 1], s2 = csr_src[i + 2], s3 = csr_src[i + 3];
        int s4 = csr_src[i + 4], s5 = csr_src[i + 5], s6 = csr_src[i + 6], s7 = csr_src[i + 7];
        float v0 = es[s0 * H + hb] + edv, v1 = es[s1 * H + hb] + edv;
        float v2 = es[s2 * H + hb] + edv, v3 = es[s3 * H + hb] + edv;
        float v4 = es[s4 * H + hb] + edv, v5 = es[s5 * H + hb] + edv;
        float v6 = es[s6 * H + hb] + edv, v7 = es[s7 * H + hb] + edv;
        v0 = v0 > 0.f ? v0 : 0.2f * v0; v1 = v1 > 0.f ? v1 : 0.2f * v1;
        v2 = v2 > 0.f ? v2 : 0.2f * v2; v3 = v3 > 0.f ? v3 : 0.2f * v3;
        v4 = v4 > 0.f ? v4 : 0.2f * v4; v5 = v5 > 0.f ? v5 : 0.2f * v5;
        v6 = v6 > 0.f ? v6 : 0.2f * v6; v7 = v7 > 0.f ? v7 : 0.2f * v7;
        float p0 = __expf(v0 - mB), p1 = __expf(v1 - mB);
        float p2 = __expf(v2 - mB), p3 = __expf(v3 - mB);
        float p4 = __expf(v4 - mB), p5 = __expf(v5 - mB);
        float p6 = __expf(v6 - mB), p7 = __expf(v7 - mB);
        float4 h0 = *reinterpret_cast<const float4*>(h + (size_t)s0 * D + f0);
        float4 h1 = *reinterpret_cast<const float4*>(h + (size_t)s1 * D + f0);
        float4 h2 = *reinterpret_cast<const float4*>(h + (size_t)s2 * D + f0);
        float4 h3 = *reinterpret_cast<const float4*>(h + (size_t)s3 * D + f0);
        float4 h4 = *reinterpret_cast<const float4*>(h + (size_t)s4 * D + f0);
        float4 h5 = *reinterpret_cast<const float4*>(h + (size_t)s5 * D + f0);
        float4 h6 = *reinterpret_cast<const float4*>(h + (size_t)s6 * D + f0);
        float4 h7 = *reinterpret_cast<const float4*>(h + (size_t)s7 * D + f0);
        acc.x += p0 * h0.x + p1 * h1.x + p2 * h2.x + p3 * h3.x
               + p4 * h4.x + p5 * h5.x + p6 * h6.x + p7 * h7.x;
        acc.y += p0 * h0.y + p1 * h1.y + p2 * h2.y + p3 * h3.y
               + p4 * h4.y + p5 * h5.y + p6 * h6.y + p7 * h7.y;
        acc.z += p0 * h0.z + p1 * h1.z + p2 * h2.z + p3 * h3.z
               + p4 * h4.z + p5 * h5.z + p6 * h6.z + p7 * h7.z;
        acc.w += p0 * h0.w + p1 * h1.w + p2 * h2.w + p3 * h3.w
               + p4 * h4.w + p5 * h5.w + p6 * h6.w + p7 * h7.w;
        sump += p0 + p1 + p2 + p3 + p4 + p5 + p6 + p7;
    }
    for (; i < end; ++i) {
        int s0 = csr_src[i];
        float v = es[s0 * H + hb] + edv;
        v = v > 0.f ? v : 0.2f * v;
        float p = __expf(v - mB);
        float4 h0 = *reinterpret_cast<const float4*>(h + (size_t)s0 * D + f0);
        acc.x += p * h0.x; acc.y += p * h0.y; acc.z += p * h0.z; acc.w += p * h0.w;
        sump += p;
    }
    float inv = 1.f / (sump + 1e-16f);
    float4 bb = *reinterpret_cast<const float4*>(b + f0);
    float4 o;
    o.x = acc.x * inv + bb.x; o.y = acc.y * inv + bb.y;
    o.z = acc.z * inv + bb.z; o.w = acc.w * inv + bb.w;
    o.x = o.x > 0.f ? o.x : 0.f; o.y = o.y > 0.f ? o.y : 0.f;
    o.z = o.z > 0.f ? o.z : 0.f; o.w = o.w > 0.f ? o.w : 0.f;
    ushort4 hv, lv;
    hv.x = f2bf(o.x); lv.x = f2bf(o.x - bf2f(hv.x));
    hv.y = f2bf(o.y); lv.y = f2bf(o.y - bf2f(hv.y));
    hv.z = f2bf(o.z); lv.z = f2bf(o.z - bf2f(hv.z));
    hv.w = f2bf(o.w); lv.w = f2bf(o.w - bf2f(hv.w));
    *reinterpret_cast<ushort4*>(Oh + (size_t)n * D + f0) = hv;
    *reinterpret_cast<ushort4*>(Ol + (size_t)n * D + f0) = lv;
}

// ---------------- final FC ----------------
__global__ __launch_bounds__(256) void fc_kernel(const u16* __restrict__ Hh,
                                                 const u16* __restrict__ Hl,
                                                 const float* __restrict__ W,
                                                 const float* __restrict__ b,
                                                 float* __restrict__ out) {
    int idx = blockIdx.x * 256 + threadIdx.x;
    if (idx >= NN * 10) return;
    int n = idx / 10, j = idx - n * 10;
    float acc = b[j];
#pragma unroll
    for (int c = 0; c < 64; ++c) {
        float hv = bf2f(Hh[n * 64 + c]) + bf2f(Hl[n * 64 + c]);
        acc += hv * W[c * 10 + j];
    }
    out[idx] = acc;
}

extern "C" void kernel_launch(void* const* d_in, const int* in_sizes, int n_in,
                              void* d_out, int out_size, void* d_ws, size_t ws_size,
                              hipStream_t stream) {
    const float* x   = (const float*)d_in[0];
    const int*   ei  = (const int*)d_in[1];
    const float* W1  = (const float*)d_in[2];
    const float* a1s = (const float*)d_in[3];
    const float* a1d = (const float*)d_in[4];
    const float* b1  = (const float*)d_in[5];
    const float* W2  = (const float*)d_in[6];
    const float* a2s = (const float*)d_in[7];
    const float* a2d = (const float*)d_in[8];
    const float* b2  = (const float*)d_in[9];
    const float* W3  = (const float*)d_in[10];
    const float* a3s = (const float*)d_in[11];
    const float* a3d = (const float*)d_in[12];
    const float* b3  = (const float*)d_in[13];
    const float* fcW = (const float*)d_in[14];
    const float* fcb = (const float*)d_in[15];
    float* out = (float*)d_out;

    // ---- workspace layout ----
    char* wp = (char*)d_ws;
    float* h   = (float*)wp;  wp += (size_t)NN * 256 * 4;     // GEMM output, f32
    u16* Ph    = (u16*)wp;    wp += (size_t)NN * 256 * 2;     // activation hi
    u16* Pl    = (u16*)wp;    wp += (size_t)NN * 256 * 2;     // activation lo
    u16* Xh    = (u16*)wp;    wp += (size_t)NN * 128 * 2;     // x hi
    u16* Xl    = (u16*)wp;    wp += (size_t)NN * 128 * 2;     // x lo
    float* ES  = (float*)wp;  wp += (size_t)NN * 4 * 4;
    float* ED  = (float*)wp;  wp += (size_t)NN * 4 * 4;
    u16* Wth   = (u16*)wp;    wp += 256 * 256 * 2;
    u16* Wtl   = (u16*)wp;    wp += 256 * 256 * 2;
    int* rowptr = (int*)wp;   wp += (NN + 1) * 4;
    int* csrsrc = (int*)wp;   wp += (size_t)E2 * 4;
    int* deg    = (int*)wp;   wp += NN * 4;
    int* bsum   = (int*)wp;   wp += 256 * 4;
    int* boff   = (int*)wp;   wp += 256 * 4;
    int* cursor = (int*)ES;                                    // alias: used pre-escore only

    // ---- build CSR ----
    fill_i32<<<(NN + 255) / 256, 256, 0, stream>>>(deg, 1, NN);
    hist_dst<<<(NE + 255) / 256, 256, 0, stream>>>(ei, deg);
    block_sums<<<SCAN_B, 256, 0, stream>>>(deg, bsum);
    scan_bsums<<<1, 256, 0, stream>>>(bsum, boff);
    scan_final<<<SCAN_B, 256, 0, stream>>>(deg, boff, rowptr, cursor);
    scatter_csr<<<(E2 + 255) / 256, 256, 0, stream>>>(ei, cursor, csrsrc);

    // ---- split input x ----
    xconv<<<(NN * IN_DIM / 4 + 255) / 256, 256, 0, stream>>>(x, Xh, Xl, NN * IN_DIM / 4);

    const int MT = (NN + 127) / 128;

    // ======== layer 1: K=128, D=256, H=4 ========
    wconv<<<(IN_DIM * 256 + 255) / 256, 256, 0, stream>>>(W1, Wth, Wtl, IN_DIM, 256);
    gemm_mfma<128, 128><<<dim3(MT, 2), 256, 0, stream>>>(Xh, Xl, Wth, Wtl, h, NN, 256);
    escore<<<NN, 256, 0, stream>>>(h, a1s, a1d, ES, ED, 4);
    agg_fused<256, 4><<<(NN + 3) / 4, 256, 0, stream>>>(rowptr, csrsrc, ES, ED, h, b1, Ph, Pl);

    // ======== layer 2: K=256, D=256, H=4 ========
    wconv<<<(256 * 256 + 255) / 256, 256, 0, stream>>>(W2, Wth, Wtl, 256, 256);
    gemm_mfma<128, 256><<<dim3(MT, 2), 256, 0, stream>>>(Ph, Pl, Wth, Wtl, h, NN, 256);
    escore<<<NN, 256, 0, stream>>>(h, a2s, a2d, ES, ED, 4);
    agg_fused<256, 4><<<(NN + 3) / 4, 256, 0, stream>>>(rowptr, csrsrc, ES, ED, h, b2, Ph, Pl);

    // ======== layer 3: K=256, D=64, H=1 ========
    wconv<<<(256 * 64 + 255) / 256, 256, 0, stream>>>(W3, Wth, Wtl, 256, 64);
    gemm_mfma<64, 256><<<dim3(MT, 1), 256, 0, stream>>>(Ph, Pl, Wth, Wtl, h, NN, 64);
    escore<<<NN, 64, 0, stream>>>(h, a3s, a3d, ES, ED, 1);
    agg_fused<64, 1><<<(NN + 15) / 16, 256, 0, stream>>>(rowptr, csrsrc, ES, ED, h, b3, Ph, Pl);

    // ======== classifier ========
    fc_kernel<<<(NN * 10 + 255) / 256, 256, 0, stream>>>(Ph, Pl, fcW, fcb, out);
}